// Round 1
// baseline (778.183 us; speedup 1.0000x reference)
//
#include <hip/hip_runtime.h>
#include <math.h>

// Problem constants
constexpr int BB = 4;       // batch
constexpr int NN = 4096;    // seq len
constexpr int CC = 512;     // channels
constexpr int HH = 8;       // heads
constexpr int DD = 64;      // head dim
constexpr int NCNT = NN - 2; // 4094 second-diff positions

// ---------------------------------------------------------------------------
// K1: second-difference sign counts over (B,C) -> peak/valley per position i
// x layout [B, N, C]; x_spec[b,c,i] = x[b,i,c]; diff along i.
// ---------------------------------------------------------------------------
__global__ void k_counts(const float* __restrict__ x,
                         int* __restrict__ peak, int* __restrict__ valley) {
  int b = blockIdx.x >> 6;     // 64 tiles per batch
  int tile = blockIdx.x & 63;
  int c = threadIdx.x;         // 512 threads, one channel each
  int lane = threadIdx.x & 63;
  for (int ii = 0; ii < 64; ++ii) {
    int i = tile * 64 + ii;
    if (i >= NCNT) break;      // uniform per block tail
    const float* xp = x + ((size_t)b * NN + i) * CC + c;
    float x0 = xp[0], x1 = xp[CC], x2 = xp[2 * CC];
    float d2 = (x2 - x1) - (x1 - x0);   // matches diff(diff(.)) rounding
    unsigned long long mneg = __ballot(d2 < 0.0f);
    unsigned long long mpos = __ballot(d2 > 0.0f);
    if (lane == 0) {
      atomicAdd(&peak[i], __popcll(mneg));
      atomicAdd(&valley[i], __popcll(mpos));
    }
  }
}

// ---------------------------------------------------------------------------
// K2a: attn[p] = sum_i peak[i]*exp(-((p-i-1)*ipw)^2) + valley[i]*exp(-(...ivw)^2)
// ---------------------------------------------------------------------------
__global__ void k_gsum(const int* __restrict__ peak, const int* __restrict__ valley,
                       const float* __restrict__ lpw, const float* __restrict__ lvw,
                       float* __restrict__ attn) {
  int p = blockIdx.x;
  int tid = threadIdx.x;  // 256
  float ipw = expf(-lpw[0]);
  float ivw = expf(-lvw[0]);
  float acc = 0.f;
  for (int i = tid; i < NCNT; i += 256) {
    float dd = (float)(p - (i + 1));
    float t1 = dd * ipw;
    float t2 = dd * ivw;
    acc += (float)peak[i] * expf(-t1 * t1) + (float)valley[i] * expf(-t2 * t2);
  }
  __shared__ float red[256];
  red[tid] = acc;
  __syncthreads();
  for (int s = 128; s > 0; s >>= 1) {
    if (tid < s) red[tid] += red[tid + s];
    __syncthreads();
  }
  if (tid == 0) attn[p] = red[0];
}

// ---------------------------------------------------------------------------
// K2b: gate = (attn - min) / (max - min + 1e-6), single block 1024 threads
// ---------------------------------------------------------------------------
__global__ void k_norm(const float* __restrict__ attn, float* __restrict__ gate) {
  int tid = threadIdx.x;  // 1024
  float v0 = attn[tid], v1 = attn[tid + 1024], v2 = attn[tid + 2048], v3 = attn[tid + 3072];
  float mn = fminf(fminf(v0, v1), fminf(v2, v3));
  float mx = fmaxf(fmaxf(v0, v1), fmaxf(v2, v3));
  __shared__ float rmn[1024], rmx[1024];
  rmn[tid] = mn; rmx[tid] = mx;
  __syncthreads();
  for (int s = 512; s > 0; s >>= 1) {
    if (tid < s) {
      rmn[tid] = fminf(rmn[tid], rmn[tid + s]);
      rmx[tid] = fmaxf(rmx[tid], rmx[tid + s]);
    }
    __syncthreads();
  }
  float lo = rmn[0];
  float denom = rmx[0] - rmn[0] + 1e-6f;
  gate[tid]        = (v0 - lo) / denom;
  gate[tid + 1024] = (v1 - lo) / denom;
  gate[tid + 2048] = (v2 - lo) / denom;
  gate[tid + 3072] = (v3 - lo) / denom;
}

// ---------------------------------------------------------------------------
// K3a: spectral PE conv path -> pe2 [64][4096]
// pe[c, m]: c<32: sin((l1-l2)*omega[c]), c>=32: cos((l1-l2)*omega[c-32]),
//   m = l1*64 + l2. Grouped conv k=3 pad=1 over flattened m, gelu(exact),
//   then 1x1 conv 128->64.
// ---------------------------------------------------------------------------
__global__ void k_pe(const float* __restrict__ omega,
                     const float* __restrict__ w1, const float* __restrict__ b1,
                     const float* __restrict__ w2, const float* __restrict__ b2,
                     float* __restrict__ pe2) {
  int n = blockIdx.x;      // 0..4095
  int j = threadIdx.x;     // 0..63
  __shared__ float pec[3][64];
  __shared__ float hs[128];
  for (int t = 0; t < 3; ++t) {
    int m = n + t - 1;
    float v = 0.f;
    if (m >= 0 && m < NN) {
      int l1 = m >> 6, l2 = m & 63;
      float rel = (float)(l1 - l2);
      v = (j < 32) ? sinf(rel * omega[j]) : cosf(rel * omega[j - 32]);
    }
    pec[t][j] = v;
  }
  __syncthreads();
  for (int o = j; o < 128; o += 64) {
    int ci = o >> 1;  // groups=64, 2 outputs per input channel
    float hv = b1[o];
    #pragma unroll
    for (int t = 0; t < 3; ++t) hv += pec[t][ci] * w1[o * 3 + t];
    hv = 0.5f * hv * (1.f + erff(hv * 0.70710678118654752f));  // exact gelu
    hs[o] = hv;
  }
  __syncthreads();
  float acc = b2[j];
  for (int o = 0; o < 128; ++o) acc += hs[o] * w2[j * 128 + o];
  pe2[(size_t)j * NN + n] = acc;
}

// ---------------------------------------------------------------------------
// K3b: channel means of pe2 -> sigmoid gate gpe[64]
// ---------------------------------------------------------------------------
__global__ void k_gatepe(const float* __restrict__ pe2,
                         const float* __restrict__ wg, const float* __restrict__ bg,
                         float* __restrict__ gpe) {
  int tid = threadIdx.x;  // 256
  int j = tid & 63, part = tid >> 6;
  float s = 0.f;
  const float* row = pe2 + (size_t)j * NN + part * 1024;
  for (int t = 0; t < 1024; ++t) s += row[t];
  __shared__ float ps[4][64];
  __shared__ float mean[64];
  ps[part][j] = s;
  __syncthreads();
  if (tid < 64) mean[j] = (ps[0][j] + ps[1][j] + ps[2][j] + ps[3][j]) * (1.f / 4096.f);
  __syncthreads();
  if (tid < 64) {
    float g = bg[j];
    for (int k2 = 0; k2 < 64; ++k2) g += wg[j * 64 + k2] * mean[k2];
    gpe[j] = 1.f / (1.f + expf(-g));
  }
}

// ---------------------------------------------------------------------------
// K3c: rope multiplier: ropem[n*64+dd] = 1 + pe2[dd,n]*gpe[l1]*64^-0.25
// NOTE reference quirk: gate indexed by l1 = n>>6 (row), not channel.
// ---------------------------------------------------------------------------
__global__ void k_ropemul(const float* __restrict__ pe2, const float* __restrict__ gpe,
                          float* __restrict__ ropem) {
  int idx = blockIdx.x * 256 + threadIdx.x;  // < 262144
  int n = idx >> 6, dd = idx & 63;
  ropem[idx] = 1.f + pe2[(size_t)dd * NN + n] * gpe[n >> 6] * 0.35355339059327373f;
}

// ---------------------------------------------------------------------------
// K4: qkv GEMM  qkv[row, col] = sum_c (x[row,c]*gate[row%N]) * wqkv[col, c] + b
// Fused epilogue: elu+1 and rope for q/k, scatter to [B,H,N,D] buffers.
// 64x64x32 tiles, block (16,16), 4x4 microtile.
// ---------------------------------------------------------------------------
__global__ __launch_bounds__(256) void k_qkv(
    const float* __restrict__ x, const float* __restrict__ gate,
    const float* __restrict__ wqkv, const float* __restrict__ bqkv,
    const float* __restrict__ ropem,
    float* __restrict__ qb, float* __restrict__ kb, float* __restrict__ vb) {
  const int m0 = blockIdx.y * 64, j0 = blockIdx.x * 64;
  const int tx = threadIdx.x, ty = threadIdx.y, tid = ty * 16 + tx;
  __shared__ float As[32][65], Bs[32][65];
  float acc[4][4] = {};
  for (int k0 = 0; k0 < CC; k0 += 32) {
    #pragma unroll
    for (int it = 0; it < 8; ++it) {
      int e = tid + 256 * it;         // 2048 elements
      int m = e >> 5, kk = e & 31;
      int row = m0 + m;
      As[kk][m] = x[(size_t)row * CC + k0 + kk] * gate[row & (NN - 1)];
      Bs[kk][m] = wqkv[(size_t)(j0 + m) * CC + k0 + kk];
    }
    __syncthreads();
    #pragma unroll
    for (int kk = 0; kk < 32; ++kk) {
      float a[4], bv[4];
      #pragma unroll
      for (int i = 0; i < 4; ++i) a[i] = As[kk][ty + 16 * i];
      #pragma unroll
      for (int j = 0; j < 4; ++j) bv[j] = Bs[kk][tx + 16 * j];
      #pragma unroll
      for (int i = 0; i < 4; ++i)
        #pragma unroll
        for (int j = 0; j < 4; ++j) acc[i][j] += a[i] * bv[j];
    }
    __syncthreads();
  }
  int b = m0 >> 12;  // rows within a block share batch (64 | 4096)
  #pragma unroll
  for (int i = 0; i < 4; ++i) {
    int row = m0 + ty + 16 * i;
    int n = row & (NN - 1);
    #pragma unroll
    for (int j = 0; j < 4; ++j) {
      int col = j0 + tx + 16 * j;
      float val = acc[i][j] + bqkv[col];
      int part = col >> 9;
      int c = col & 511;
      int h = c >> 6, dd = c & 63;
      size_t oi = (((size_t)b * HH + h) * NN + n) * DD + dd;
      if (part == 0) {
        val = (val > 0.f) ? (val + 1.f) : (expm1f(val) + 1.f);  // elu+1
        qb[oi] = val * ropem[n * 64 + dd];
      } else if (part == 1) {
        val = (val > 0.f) ? (val + 1.f) : (expm1f(val) + 1.f);
        kb[oi] = val * ropem[n * 64 + dd];
      } else {
        vb[oi] = val;
      }
    }
  }
}

// ---------------------------------------------------------------------------
// K5a: ctx partials: for (b,h,chunk): sum over 256 n of q[n,d]*k[n,e] * scale
// ---------------------------------------------------------------------------
__global__ __launch_bounds__(256) void k_ctx_part(
    const float* __restrict__ qb, const float* __restrict__ kb,
    float* __restrict__ ctxp) {
  int bh = blockIdx.x >> 4;
  int chunk = blockIdx.x & 15;
  const int tx = threadIdx.x, ty = threadIdx.y, tid = ty * 16 + tx;
  __shared__ float Qs[16][68], Ks[16][68];
  float acc[4][4] = {};
  const size_t base = (size_t)bh * NN * DD;
  for (int n0 = chunk * 256; n0 < chunk * 256 + 256; n0 += 16) {
    int idx4 = tid * 4;                 // 1024 floats per buffer
    int nl = idx4 >> 6, dd = idx4 & 63;
    *(float4*)&Qs[nl][dd] = *(const float4*)&qb[base + (size_t)(n0 + nl) * DD + dd];
    *(float4*)&Ks[nl][dd] = *(const float4*)&kb[base + (size_t)(n0 + nl) * DD + dd];
    __syncthreads();
    #pragma unroll
    for (int nn2 = 0; nn2 < 16; ++nn2) {
      float a[4], bv[4];
      #pragma unroll
      for (int i = 0; i < 4; ++i) a[i] = Qs[nn2][ty + 16 * i];
      #pragma unroll
      for (int j = 0; j < 4; ++j) bv[j] = Ks[nn2][tx + 16 * j];
      #pragma unroll
      for (int i = 0; i < 4; ++i)
        #pragma unroll
        for (int j = 0; j < 4; ++j) acc[i][j] += a[i] * bv[j];
    }
    __syncthreads();
  }
  const float scale = 1.f / 512.f;
  #pragma unroll
  for (int i = 0; i < 4; ++i)
    #pragma unroll
    for (int j = 0; j < 4; ++j)
      ctxp[(size_t)(bh * 16 + chunk) * 4096 + (ty + 16 * i) * 64 + (tx + 16 * j)] =
          acc[i][j] * scale;
}

// K5b: deterministic reduce of 16 chunks -> ctx[bh][64][64]
__global__ void k_ctx_red(const float* __restrict__ ctxp, float* __restrict__ ctx) {
  int bh = blockIdx.x;
  int tid = threadIdx.x;  // 256
  for (int r = 0; r < 16; ++r) {
    int idx = tid + 256 * r;
    float s = 0.f;
    for (int c2 = 0; c2 < 16; ++c2) s += ctxp[(size_t)(bh * 16 + c2) * 4096 + idx];
    ctx[(size_t)bh * 4096 + idx] = s;
  }
}

// ---------------------------------------------------------------------------
// K6: out[n,e] = scale * sum_d v[n,d]*ctx[d,e]; write as [B,N,C] (head-interleave)
// ---------------------------------------------------------------------------
__global__ __launch_bounds__(256) void k_out(
    const float* __restrict__ vb, const float* __restrict__ ctx,
    float* __restrict__ aout) {
  int bh = blockIdx.x >> 6;
  int t = blockIdx.x & 63;  // n-tile of 64
  int b = bh >> 3, h = bh & 7;
  const int tx = threadIdx.x, ty = threadIdx.y, tid = ty * 16 + tx;
  __shared__ float Vs[64][68], Cs[64][68];
  #pragma unroll
  for (int it = 0; it < 4; ++it) {
    int idx4 = (tid + 256 * it) * 4;  // 0..4095
    int r = idx4 >> 6, cc = idx4 & 63;
    *(float4*)&Cs[r][cc] = *(const float4*)&ctx[(size_t)bh * 4096 + idx4];
    *(float4*)&Vs[r][cc] = *(const float4*)&vb[((size_t)bh * NN + t * 64 + r) * DD + cc];
  }
  __syncthreads();
  float acc[4][4] = {};
  for (int d2 = 0; d2 < 64; ++d2) {
    float a[4], bv[4];
    #pragma unroll
    for (int i = 0; i < 4; ++i) a[i] = Vs[ty + 16 * i][d2];
    #pragma unroll
    for (int j = 0; j < 4; ++j) bv[j] = Cs[d2][tx + 16 * j];
    #pragma unroll
    for (int i = 0; i < 4; ++i)
      #pragma unroll
      for (int j = 0; j < 4; ++j) acc[i][j] += a[i] * bv[j];
  }
  const float scale = 1.f / 512.f;
  #pragma unroll
  for (int i = 0; i < 4; ++i)
    #pragma unroll
    for (int j = 0; j < 4; ++j)
      aout[((size_t)b * NN + t * 64 + ty + 16 * i) * CC + h * 64 + tx + 16 * j] =
          acc[i][j] * scale;
}

// ---------------------------------------------------------------------------
// K7: proj GEMM  out[row, e] = sum_c aout[row,c] * wproj[e,c] + bproj[e]
// ---------------------------------------------------------------------------
__global__ __launch_bounds__(256) void k_proj(
    const float* __restrict__ Ain, const float* __restrict__ w,
    const float* __restrict__ bias, float* __restrict__ out) {
  const int m0 = blockIdx.y * 64, j0 = blockIdx.x * 64;
  const int tx = threadIdx.x, ty = threadIdx.y, tid = ty * 16 + tx;
  __shared__ float As[32][65], Bs[32][65];
  float acc[4][4] = {};
  for (int k0 = 0; k0 < CC; k0 += 32) {
    #pragma unroll
    for (int it = 0; it < 8; ++it) {
      int e = tid + 256 * it;
      int m = e >> 5, kk = e & 31;
      As[kk][m] = Ain[(size_t)(m0 + m) * CC + k0 + kk];
      Bs[kk][m] = w[(size_t)(j0 + m) * CC + k0 + kk];
    }
    __syncthreads();
    #pragma unroll
    for (int kk = 0; kk < 32; ++kk) {
      float a[4], bv[4];
      #pragma unroll
      for (int i = 0; i < 4; ++i) a[i] = As[kk][ty + 16 * i];
      #pragma unroll
      for (int j = 0; j < 4; ++j) bv[j] = Bs[kk][tx + 16 * j];
      #pragma unroll
      for (int i = 0; i < 4; ++i)
        #pragma unroll
        for (int j = 0; j < 4; ++j) acc[i][j] += a[i] * bv[j];
    }
    __syncthreads();
  }
  #pragma unroll
  for (int i = 0; i < 4; ++i) {
    int row = m0 + ty + 16 * i;
    #pragma unroll
    for (int j = 0; j < 4; ++j) {
      int col = j0 + tx + 16 * j;
      out[(size_t)row * CC + col] = acc[i][j] + bias[col];
    }
  }
}

// ---------------------------------------------------------------------------
extern "C" void kernel_launch(void* const* d_in, const int* in_sizes, int n_in,
                              void* d_out, int out_size, void* d_ws, size_t ws_size,
                              hipStream_t stream) {
  const float* x    = (const float*)d_in[0];
  const float* lpw  = (const float*)d_in[1];
  const float* lvw  = (const float*)d_in[2];
  const float* wqkv = (const float*)d_in[3];
  const float* bqkv = (const float*)d_in[4];
  const float* wproj= (const float*)d_in[5];
  const float* bproj= (const float*)d_in[6];
  const float* omega= (const float*)d_in[7];
  const float* w1   = (const float*)d_in[8];
  const float* b1   = (const float*)d_in[9];
  const float* w2   = (const float*)d_in[10];
  const float* b2   = (const float*)d_in[11];
  const float* wg   = (const float*)d_in[12];
  const float* bg   = (const float*)d_in[13];
  float* out = (float*)d_out;

  // workspace layout (floats)
  float* ws = (float*)d_ws;
  int*   peak   = (int*)ws;                 // 4096
  int*   valley = (int*)(ws + 4096);        // 4096
  float* attn   = ws + 8192;                // 4096
  float* gate   = ws + 12288;               // 4096
  float* pe2    = ws + 16384;               // 262144
  float* gpe    = ws + 278528;              // 64 (pad to 128)
  float* ropem  = ws + 278656;              // 262144
  float* qb     = ws + 540800;              // 8388608
  float* kb     = qb + 8388608;             // 8388608
  float* vb     = kb + 8388608;             // 8388608
  float* ctxp   = vb + 8388608;             // 2097152
  float* ctx    = ctxp + 2097152;           // 131072
  float* aout   = qb;                       // alias: q dead after k_ctx_part

  hipMemsetAsync(peak, 0, 2 * 4096 * sizeof(int), stream);

  k_counts<<<BB * 64, 512, 0, stream>>>(x, peak, valley);
  k_gsum<<<NN, 256, 0, stream>>>(peak, valley, lpw, lvw, attn);
  k_norm<<<1, 1024, 0, stream>>>(attn, gate);
  k_pe<<<NN, 64, 0, stream>>>(omega, w1, b1, w2, b2, pe2);
  k_gatepe<<<1, 256, 0, stream>>>(pe2, wg, bg, gpe);
  k_ropemul<<<1024, 256, 0, stream>>>(pe2, gpe, ropem);
  k_qkv<<<dim3(24, 256), dim3(16, 16), 0, stream>>>(x, gate, wqkv, bqkv, ropem,
                                                    qb, kb, vb);
  k_ctx_part<<<512, dim3(16, 16), 0, stream>>>(qb, kb, ctxp);
  k_ctx_red<<<32, 256, 0, stream>>>(ctxp, ctx);
  k_out<<<2048, dim3(16, 16), 0, stream>>>(vb, ctx, aout);
  k_proj<<<dim3(8, 256), dim3(16, 16), 0, stream>>>(aout, wproj, bproj, out);
}

// Round 2
// 345.820 us; speedup vs baseline: 2.2503x; 2.2503x over previous
//
#include <hip/hip_runtime.h>
#include <hip/hip_bf16.h>
#include <math.h>

// Problem constants
constexpr int BB = 4;       // batch
constexpr int NN = 4096;    // seq len
constexpr int CC = 512;     // channels
constexpr int HH = 8;       // heads
constexpr int DD = 64;      // head dim
constexpr int NCNT = NN - 2;

typedef __bf16 bf16x8 __attribute__((ext_vector_type(8)));
typedef float f32x4 __attribute__((ext_vector_type(4)));

__device__ __forceinline__ float b2f(ushort u) {
  unsigned v = ((unsigned)u) << 16;
  return __builtin_bit_cast(float, v);
}
__device__ __forceinline__ ushort f2b(float f) {
  __hip_bfloat16 h = __float2bfloat16(f);
  return __builtin_bit_cast(ushort, h);
}
__device__ __forceinline__ void gload16(const ushort* g, ushort* l) {
  __builtin_amdgcn_global_load_lds(
      (const __attribute__((address_space(1))) unsigned int*)g,
      (__attribute__((address_space(3))) unsigned int*)l, 16, 0, 0);
}

// ---------------------------------------------------------------------------
// K1: second-difference sign counts over (B,C)
// ---------------------------------------------------------------------------
__global__ void k_counts(const float* __restrict__ x,
                         int* __restrict__ peak, int* __restrict__ valley) {
  int b = blockIdx.x >> 6;
  int tile = blockIdx.x & 63;
  int c = threadIdx.x;
  int lane = threadIdx.x & 63;
  for (int ii = 0; ii < 64; ++ii) {
    int i = tile * 64 + ii;
    if (i >= NCNT) break;
    const float* xp = x + ((size_t)b * NN + i) * CC + c;
    float x0 = xp[0], x1 = xp[CC], x2 = xp[2 * CC];
    float d2 = (x2 - x1) - (x1 - x0);
    unsigned long long mneg = __ballot(d2 < 0.0f);
    unsigned long long mpos = __ballot(d2 > 0.0f);
    if (lane == 0) {
      atomicAdd(&peak[i], __popcll(mneg));
      atomicAdd(&valley[i], __popcll(mpos));
    }
  }
}

// ---------------------------------------------------------------------------
// K2a: Gaussian sums
// ---------------------------------------------------------------------------
__global__ void k_gsum(const int* __restrict__ peak, const int* __restrict__ valley,
                       const float* __restrict__ lpw, const float* __restrict__ lvw,
                       float* __restrict__ attn) {
  int p = blockIdx.x;
  int tid = threadIdx.x;
  float ipw = expf(-lpw[0]);
  float ivw = expf(-lvw[0]);
  float acc = 0.f;
  for (int i = tid; i < NCNT; i += 256) {
    float dd = (float)(p - (i + 1));
    float t1 = dd * ipw;
    float t2 = dd * ivw;
    acc += (float)peak[i] * expf(-t1 * t1) + (float)valley[i] * expf(-t2 * t2);
  }
  __shared__ float red[256];
  red[tid] = acc;
  __syncthreads();
  for (int s = 128; s > 0; s >>= 1) {
    if (tid < s) red[tid] += red[tid + s];
    __syncthreads();
  }
  if (tid == 0) attn[p] = red[0];
}

// ---------------------------------------------------------------------------
// K2b: min-max normalize
// ---------------------------------------------------------------------------
__global__ void k_norm(const float* __restrict__ attn, float* __restrict__ gate) {
  int tid = threadIdx.x;  // 1024
  float v0 = attn[tid], v1 = attn[tid + 1024], v2 = attn[tid + 2048], v3 = attn[tid + 3072];
  float mn = fminf(fminf(v0, v1), fminf(v2, v3));
  float mx = fmaxf(fmaxf(v0, v1), fmaxf(v2, v3));
  __shared__ float rmn[1024], rmx[1024];
  rmn[tid] = mn; rmx[tid] = mx;
  __syncthreads();
  for (int s = 512; s > 0; s >>= 1) {
    if (tid < s) {
      rmn[tid] = fminf(rmn[tid], rmn[tid + s]);
      rmx[tid] = fmaxf(rmx[tid], rmx[tid + s]);
    }
    __syncthreads();
  }
  float lo = rmn[0];
  float denom = rmx[0] - rmn[0] + 1e-6f;
  gate[tid]        = (v0 - lo) / denom;
  gate[tid + 1024] = (v1 - lo) / denom;
  gate[tid + 2048] = (v2 - lo) / denom;
  gate[tid + 3072] = (v3 - lo) / denom;
}

// ---------------------------------------------------------------------------
// K3a: spectral PE conv path -> pe2 [64][4096]
// ---------------------------------------------------------------------------
__global__ void k_pe(const float* __restrict__ omega,
                     const float* __restrict__ w1, const float* __restrict__ b1,
                     const float* __restrict__ w2, const float* __restrict__ b2,
                     float* __restrict__ pe2) {
  int n = blockIdx.x;
  int j = threadIdx.x;  // 64
  __shared__ float pec[3][64];
  __shared__ float hs[128];
  for (int t = 0; t < 3; ++t) {
    int m = n + t - 1;
    float v = 0.f;
    if (m >= 0 && m < NN) {
      int l1 = m >> 6, l2 = m & 63;
      float rel = (float)(l1 - l2);
      v = (j < 32) ? sinf(rel * omega[j]) : cosf(rel * omega[j - 32]);
    }
    pec[t][j] = v;
  }
  __syncthreads();
  for (int o = j; o < 128; o += 64) {
    int ci = o >> 1;
    float hv = b1[o];
    #pragma unroll
    for (int t = 0; t < 3; ++t) hv += pec[t][ci] * w1[o * 3 + t];
    hv = 0.5f * hv * (1.f + erff(hv * 0.70710678118654752f));
    hs[o] = hv;
  }
  __syncthreads();
  float acc = b2[j];
  for (int o = 0; o < 128; ++o) acc += hs[o] * w2[j * 128 + o];
  pe2[(size_t)j * NN + n] = acc;
}

// ---------------------------------------------------------------------------
// K3b: channel means -> sigmoid gate gpe[64]
// ---------------------------------------------------------------------------
__global__ void k_gatepe(const float* __restrict__ pe2,
                         const float* __restrict__ wg, const float* __restrict__ bg,
                         float* __restrict__ gpe) {
  int tid = threadIdx.x;  // 256
  int j = tid & 63, part = tid >> 6;
  float s = 0.f;
  const float* row = pe2 + (size_t)j * NN + part * 1024;
  for (int t = 0; t < 1024; ++t) s += row[t];
  __shared__ float ps[4][64];
  __shared__ float mean[64];
  ps[part][j] = s;
  __syncthreads();
  if (tid < 64) mean[j] = (ps[0][j] + ps[1][j] + ps[2][j] + ps[3][j]) * (1.f / 4096.f);
  __syncthreads();
  if (tid < 64) {
    float g = bg[j];
    for (int k2 = 0; k2 < 64; ++k2) g += wg[j * 64 + k2] * mean[k2];
    gpe[j] = 1.f / (1.f + expf(-g));
  }
}

// ---------------------------------------------------------------------------
// K3c: rope multiplier
// ---------------------------------------------------------------------------
__global__ void k_ropemul(const float* __restrict__ pe2, const float* __restrict__ gpe,
                          float* __restrict__ ropem) {
  int idx = blockIdx.x * 256 + threadIdx.x;
  int n = idx >> 6, dd = idx & 63;
  ropem[idx] = 1.f + pe2[(size_t)dd * NN + n] * gpe[n >> 6] * 0.35355339059327373f;
}

// ---------------------------------------------------------------------------
// Prep: A = x*gate -> bf16 hi/lo split
// ---------------------------------------------------------------------------
__global__ void k_prep_a(const float* __restrict__ x, const float* __restrict__ gate,
                         ushort* __restrict__ Ah, ushort* __restrict__ Al) {
  int idx4 = (blockIdx.x * 256 + threadIdx.x) * 4;
  int row = idx4 >> 9;
  float g = gate[row & (NN - 1)];
  float4 v = *(const float4*)&x[idx4];
  float vv[4] = {v.x * g, v.y * g, v.z * g, v.w * g};
  ushort4 ah, al;
  ushort* ap = (ushort*)&ah;
  ushort* lp = (ushort*)&al;
  #pragma unroll
  for (int i = 0; i < 4; ++i) {
    ap[i] = f2b(vv[i]);
    lp[i] = f2b(vv[i] - b2f(ap[i]));
  }
  *(ushort4*)&Ah[idx4] = ah;
  *(ushort4*)&Al[idx4] = al;
}

// Prep: generic f32 -> bf16 hi/lo
__global__ void k_prep_s(const float* __restrict__ src,
                         ushort* __restrict__ Sh, ushort* __restrict__ Sl, int nelem) {
  int idx4 = (blockIdx.x * 256 + threadIdx.x) * 4;
  if (idx4 >= nelem) return;
  float4 v = *(const float4*)&src[idx4];
  float vv[4] = {v.x, v.y, v.z, v.w};
  ushort4 ah, al;
  ushort* ap = (ushort*)&ah;
  ushort* lp = (ushort*)&al;
  #pragma unroll
  for (int i = 0; i < 4; ++i) {
    ap[i] = f2b(vv[i]);
    lp[i] = f2b(vv[i] - b2f(ap[i]));
  }
  *(ushort4*)&Sh[idx4] = ah;
  *(ushort4*)&Sl[idx4] = al;
}

// ---------------------------------------------------------------------------
// bf16x3 MFMA GEMM: C[M][ncols] = A[M][512] * B[ncols][512]^T (+bias)
// 128x128 tile, BK=32, 4 waves (2x2), each wave 64x64 via 4x4 16x16x32 frags.
// EPI=0: plain f32 out [row*ncols+col]. EPI=1: qkv epilogue (elu+1, rope,
//   q/k -> bf16 [B,H,N,D], v -> f32 [B,H,N,D]).
// ---------------------------------------------------------------------------
template <int EPI>
__global__ __launch_bounds__(256) void k_gemm3(
    const ushort* __restrict__ Agh, const ushort* __restrict__ Agl,
    const ushort* __restrict__ Bgh, const ushort* __restrict__ Bgl,
    const float* __restrict__ bias, const float* __restrict__ ropem,
    float* __restrict__ outF, ushort* __restrict__ qb, ushort* __restrict__ kb,
    int ncols) {
  const int m0 = blockIdx.y * 128, n0 = blockIdx.x * 128;
  const int tid = threadIdx.x, wave = tid >> 6, lane = tid & 63;
  const int wm = wave >> 1, wn = wave & 1;
  __shared__ ushort sAh[4096], sAl[4096], sBh[4096], sBl[4096];  // [128][32] each
  f32x4 acc[4][4] = {};
  const int srow = lane >> 2;
  const int scol = (lane & 3) * 8;  // element offset (8 bf16 = 16B)

  for (int k0 = 0; k0 < CC; k0 += 32) {
    #pragma unroll
    for (int j = 0; j < 2; ++j) {
      int chunk = wave * 2 + j;              // wave-uniform
      int row = chunk * 16 + srow;
      size_t ga = (size_t)(m0 + row) * CC + k0 + scol;
      size_t gb = (size_t)(n0 + row) * CC + k0 + scol;
      gload16(Agh + ga, sAh + chunk * 512);
      gload16(Agl + ga, sAl + chunk * 512);
      gload16(Bgh + gb, sBh + chunk * 512);
      gload16(Bgl + gb, sBl + chunk * 512);
    }
    __syncthreads();
    bf16x8 ah[4], alo[4], bh[4], blo[4];
    #pragma unroll
    for (int m = 0; m < 4; ++m) {
      int off = (wm * 64 + m * 16 + (lane & 15)) * 32 + (lane >> 4) * 8;
      ah[m] = *(const bf16x8*)(sAh + off);
      alo[m] = *(const bf16x8*)(sAl + off);
    }
    #pragma unroll
    for (int n = 0; n < 4; ++n) {
      int off = (wn * 64 + n * 16 + (lane & 15)) * 32 + (lane >> 4) * 8;
      bh[n] = *(const bf16x8*)(sBh + off);
      blo[n] = *(const bf16x8*)(sBl + off);
    }
    #pragma unroll
    for (int m = 0; m < 4; ++m)
      #pragma unroll
      for (int n = 0; n < 4; ++n) {
        acc[m][n] = __builtin_amdgcn_mfma_f32_16x16x32_bf16(ah[m], bh[n], acc[m][n], 0, 0, 0);
        acc[m][n] = __builtin_amdgcn_mfma_f32_16x16x32_bf16(alo[m], bh[n], acc[m][n], 0, 0, 0);
        acc[m][n] = __builtin_amdgcn_mfma_f32_16x16x32_bf16(ah[m], blo[n], acc[m][n], 0, 0, 0);
      }
    __syncthreads();
  }

  #pragma unroll
  for (int m = 0; m < 4; ++m) {
    #pragma unroll
    for (int n = 0; n < 4; ++n) {
      #pragma unroll
      for (int r = 0; r < 4; ++r) {
        int row = m0 + wm * 64 + m * 16 + (lane >> 4) * 4 + r;
        int col = n0 + wn * 64 + n * 16 + (lane & 15);
        float val = acc[m][n][r] + bias[col];
        if (EPI == 0) {
          outF[(size_t)row * ncols + col] = val;
        } else {
          int nseq = row & (NN - 1), b = row >> 12;
          int part = col >> 9, c = col & 511, h = c >> 6, dd = c & 63;
          size_t oi = (((size_t)b * HH + h) * NN + nseq) * DD + dd;
          if (part == 2) {
            outF[oi] = val;  // v, f32
          } else {
            float e = val > 0.f ? val + 1.f : expf(val);  // elu+1
            float res = e * ropem[nseq * 64 + dd];
            (part == 0 ? qb : kb)[oi] = f2b(res);
          }
        }
      }
    }
  }
}

// ---------------------------------------------------------------------------
// K5a: ctx partials (reads bf16 q/k, f32 math)
// ---------------------------------------------------------------------------
__global__ __launch_bounds__(256) void k_ctx_part(
    const ushort* __restrict__ qb, const ushort* __restrict__ kb,
    float* __restrict__ ctxp) {
  int bh = blockIdx.x >> 4;
  int chunk = blockIdx.x & 15;
  const int tx = threadIdx.x, ty = threadIdx.y, tid = ty * 16 + tx;
  __shared__ float Qs[16][68], Ks[16][68];
  float acc[4][4] = {};
  const size_t base = (size_t)bh * NN * DD;
  for (int n0 = chunk * 256; n0 < chunk * 256 + 256; n0 += 16) {
    int idx4 = tid * 4;
    int nl = idx4 >> 6, dd = idx4 & 63;
    ushort4 qv = *(const ushort4*)&qb[base + (size_t)(n0 + nl) * DD + dd];
    ushort4 kv = *(const ushort4*)&kb[base + (size_t)(n0 + nl) * DD + dd];
    Qs[nl][dd] = b2f(qv.x); Qs[nl][dd + 1] = b2f(qv.y);
    Qs[nl][dd + 2] = b2f(qv.z); Qs[nl][dd + 3] = b2f(qv.w);
    Ks[nl][dd] = b2f(kv.x); Ks[nl][dd + 1] = b2f(kv.y);
    Ks[nl][dd + 2] = b2f(kv.z); Ks[nl][dd + 3] = b2f(kv.w);
    __syncthreads();
    #pragma unroll
    for (int nn2 = 0; nn2 < 16; ++nn2) {
      float a[4], bv[4];
      #pragma unroll
      for (int i = 0; i < 4; ++i) a[i] = Qs[nn2][ty + 16 * i];
      #pragma unroll
      for (int j = 0; j < 4; ++j) bv[j] = Ks[nn2][tx + 16 * j];
      #pragma unroll
      for (int i = 0; i < 4; ++i)
        #pragma unroll
        for (int j = 0; j < 4; ++j) acc[i][j] += a[i] * bv[j];
    }
    __syncthreads();
  }
  const float scale = 1.f / 512.f;
  #pragma unroll
  for (int i = 0; i < 4; ++i)
    #pragma unroll
    for (int j = 0; j < 4; ++j)
      ctxp[(size_t)(bh * 16 + chunk) * 4096 + (ty + 16 * i) * 64 + (tx + 16 * j)] =
          acc[i][j] * scale;
}

// K5b: deterministic reduce
__global__ void k_ctx_red(const float* __restrict__ ctxp, float* __restrict__ ctx) {
  int bh = blockIdx.x;
  int tid = threadIdx.x;
  for (int r = 0; r < 16; ++r) {
    int idx = tid + 256 * r;
    float s = 0.f;
    for (int c2 = 0; c2 < 16; ++c2) s += ctxp[(size_t)(bh * 16 + c2) * 4096 + idx];
    ctx[(size_t)bh * 4096 + idx] = s;
  }
}

// ---------------------------------------------------------------------------
// K6: out[n,e] = scale * sum_d v[n,d]*ctx[d,e] -> [B,N,C]
// ---------------------------------------------------------------------------
__global__ __launch_bounds__(256) void k_out(
    const float* __restrict__ vb, const float* __restrict__ ctx,
    float* __restrict__ aout) {
  int bh = blockIdx.x >> 6;
  int t = blockIdx.x & 63;
  int b = bh >> 3, h = bh & 7;
  const int tx = threadIdx.x, ty = threadIdx.y, tid = ty * 16 + tx;
  __shared__ float Vs[64][68], Cs[64][68];
  #pragma unroll
  for (int it = 0; it < 4; ++it) {
    int idx4 = (tid + 256 * it) * 4;
    int r = idx4 >> 6, cc = idx4 & 63;
    *(float4*)&Cs[r][cc] = *(const float4*)&ctx[(size_t)bh * 4096 + idx4];
    *(float4*)&Vs[r][cc] = *(const float4*)&vb[((size_t)bh * NN + t * 64 + r) * DD + cc];
  }
  __syncthreads();
  float acc[4][4] = {};
  for (int d2 = 0; d2 < 64; ++d2) {
    float a[4], bv[4];
    #pragma unroll
    for (int i = 0; i < 4; ++i) a[i] = Vs[ty + 16 * i][d2];
    #pragma unroll
    for (int j = 0; j < 4; ++j) bv[j] = Cs[d2][tx + 16 * j];
    #pragma unroll
    for (int i = 0; i < 4; ++i)
      #pragma unroll
      for (int j = 0; j < 4; ++j) acc[i][j] += a[i] * bv[j];
  }
  const float scale = 1.f / 512.f;
  #pragma unroll
  for (int i = 0; i < 4; ++i)
    #pragma unroll
    for (int j = 0; j < 4; ++j)
      aout[((size_t)b * NN + t * 64 + ty + 16 * i) * CC + h * 64 + tx + 16 * j] =
          acc[i][j] * scale;
}

// ---------------------------------------------------------------------------
extern "C" void kernel_launch(void* const* d_in, const int* in_sizes, int n_in,
                              void* d_out, int out_size, void* d_ws, size_t ws_size,
                              hipStream_t stream) {
  const float* x    = (const float*)d_in[0];
  const float* lpw  = (const float*)d_in[1];
  const float* lvw  = (const float*)d_in[2];
  const float* wqkv = (const float*)d_in[3];
  const float* bqkv = (const float*)d_in[4];
  const float* wproj= (const float*)d_in[5];
  const float* bproj= (const float*)d_in[6];
  const float* omega= (const float*)d_in[7];
  const float* w1   = (const float*)d_in[8];
  const float* b1   = (const float*)d_in[9];
  const float* w2   = (const float*)d_in[10];
  const float* b2   = (const float*)d_in[11];
  const float* wg   = (const float*)d_in[12];
  const float* bg   = (const float*)d_in[13];
  float* out = (float*)d_out;

  constexpr size_t MB = 1024 * 1024;
  char* w = (char*)d_ws;
  int*   peak   = (int*)(w);
  int*   valley = (int*)(w + 16 * 1024);
  float* attn   = (float*)(w + 32 * 1024);
  float* gate   = (float*)(w + 48 * 1024);
  float* pe2    = (float*)(w + 64 * 1024);        // 1 MiB
  float* gpe    = (float*)(w + 1088 * 1024);
  float* ropem  = (float*)(w + 1152 * 1024);      // 1 MiB
  ushort* qb    = (ushort*)(w + 4 * MB);          // 16 MiB bf16 [B,H,N,D]
  ushort* kb    = (ushort*)(w + 20 * MB);         // 16 MiB
  float*  vb    = (float*)(w + 36 * MB);          // 32 MiB f32 [B,H,N,D]
  ushort* Ah    = (ushort*)(w + 68 * MB);         // 16 MiB
  ushort* Al    = (ushort*)(w + 84 * MB);         // 16 MiB
  ushort* Wh    = (ushort*)(w + 100 * MB);        // 1.5 MiB
  ushort* Wl    = (ushort*)(w + 102 * MB);        // 1.5 MiB
  ushort* Ph    = (ushort*)(w + 104 * MB);        // 0.5 MiB
  ushort* Pl    = (ushort*)(w + 105 * MB);        // 0.5 MiB -> end 105.5 MiB
  // aliases (sequential reuse, same stream ordering):
  float* ctxp = (float*)(w + 68 * MB);            // over Ah (dead after qkv gemm)
  float* ctx  = (float*)(w + 84 * MB);            // over Al
  float* aout = (float*)(w + 4 * MB);             // over qb+kb (dead after ctx)
  ushort* Aoh = (ushort*)(w + 68 * MB);           // over ctxp (dead after ctx_red)
  ushort* Aol = (ushort*)(w + 84 * MB);           // over ctx (dead after k_out)

  hipMemsetAsync(peak, 0, 2 * 4096 * sizeof(int), stream);

  k_counts<<<BB * 64, 512, 0, stream>>>(x, peak, valley);
  k_gsum<<<NN, 256, 0, stream>>>(peak, valley, lpw, lvw, attn);
  k_norm<<<1, 1024, 0, stream>>>(attn, gate);
  k_pe<<<NN, 64, 0, stream>>>(omega, w1, b1, w2, b2, pe2);
  k_gatepe<<<1, 256, 0, stream>>>(pe2, wg, bg, gpe);
  k_ropemul<<<1024, 256, 0, stream>>>(pe2, gpe, ropem);

  k_prep_a<<<8192, 256, 0, stream>>>(x, gate, Ah, Al);
  k_prep_s<<<768, 256, 0, stream>>>(wqkv, Wh, Wl, 3 * CC * CC);
  k_prep_s<<<256, 256, 0, stream>>>(wproj, Ph, Pl, CC * CC);

  // qkv: M=16384, N=1536
  k_gemm3<1><<<dim3(12, 128), 256, 0, stream>>>(Ah, Al, Wh, Wl, bqkv, ropem,
                                                vb, qb, kb, 0);
  k_ctx_part<<<512, dim3(16, 16), 0, stream>>>(qb, kb, ctxp);
  k_ctx_red<<<32, 256, 0, stream>>>(ctxp, ctx);
  k_out<<<2048, dim3(16, 16), 0, stream>>>(vb, ctx, aout);

  k_prep_s<<<8192, 256, 0, stream>>>(aout, Aoh, Aol, NN * BB * CC);
  // proj: M=16384, N=512
  k_gemm3<0><<<dim3(4, 128), 256, 0, stream>>>(Aoh, Aol, Ph, Pl, bproj, nullptr,
                                               out, nullptr, nullptr, CC);
}

// Round 3
// 290.982 us; speedup vs baseline: 2.6743x; 1.1885x over previous
//
#include <hip/hip_runtime.h>
#include <hip/hip_bf16.h>
#include <math.h>

constexpr int BB = 4;
constexpr int NN = 4096;
constexpr int CC = 512;
constexpr int HH = 8;
constexpr int DD = 64;
constexpr int NCNT = NN - 2;

typedef __bf16 bf16x8 __attribute__((ext_vector_type(8)));
typedef float f32x4 __attribute__((ext_vector_type(4)));

__device__ __forceinline__ float b2f(ushort u) {
  unsigned v = ((unsigned)u) << 16;
  return __builtin_bit_cast(float, v);
}
__device__ __forceinline__ ushort f2b(float f) {
  __hip_bfloat16 h = __float2bfloat16(f);
  return __builtin_bit_cast(ushort, h);
}
__device__ __forceinline__ void gload16(const ushort* g, ushort* l) {
  __builtin_amdgcn_global_load_lds(
      (const __attribute__((address_space(1))) unsigned int*)g,
      (__attribute__((address_space(3))) unsigned int*)l, 16, 0, 0);
}

// ---------------------------------------------------------------------------
// K1: second-difference sign counts
// ---------------------------------------------------------------------------
__global__ void k_counts(const float* __restrict__ x,
                         int* __restrict__ peak, int* __restrict__ valley) {
  int b = blockIdx.x >> 6;
  int tile = blockIdx.x & 63;
  int c = threadIdx.x;
  int lane = threadIdx.x & 63;
  for (int ii = 0; ii < 64; ++ii) {
    int i = tile * 64 + ii;
    if (i >= NCNT) break;
    const float* xp = x + ((size_t)b * NN + i) * CC + c;
    float x0 = xp[0], x1 = xp[CC], x2 = xp[2 * CC];
    float d2 = (x2 - x1) - (x1 - x0);
    unsigned long long mneg = __ballot(d2 < 0.0f);
    unsigned long long mpos = __ballot(d2 > 0.0f);
    if (lane == 0) {
      atomicAdd(&peak[i], __popcll(mneg));
      atomicAdd(&valley[i], __popcll(mpos));
    }
  }
}

// ---------------------------------------------------------------------------
// K2a: Gaussian sums
// ---------------------------------------------------------------------------
__global__ void k_gsum(const int* __restrict__ peak, const int* __restrict__ valley,
                       const float* __restrict__ lpw, const float* __restrict__ lvw,
                       float* __restrict__ attn) {
  int p = blockIdx.x;
  int tid = threadIdx.x;
  float ipw = expf(-lpw[0]);
  float ivw = expf(-lvw[0]);
  float acc = 0.f;
  for (int i = tid; i < NCNT; i += 256) {
    float dd = (float)(p - (i + 1));
    float t1 = dd * ipw;
    float t2 = dd * ivw;
    acc += (float)peak[i] * expf(-t1 * t1) + (float)valley[i] * expf(-t2 * t2);
  }
  __shared__ float red[256];
  red[tid] = acc;
  __syncthreads();
  for (int s = 128; s > 0; s >>= 1) {
    if (tid < s) red[tid] += red[tid + s];
    __syncthreads();
  }
  if (tid == 0) attn[p] = red[0];
}

// ---------------------------------------------------------------------------
// K2b: min-max normalize
// ---------------------------------------------------------------------------
__global__ void k_norm(const float* __restrict__ attn, float* __restrict__ gate) {
  int tid = threadIdx.x;  // 1024
  float v0 = attn[tid], v1 = attn[tid + 1024], v2 = attn[tid + 2048], v3 = attn[tid + 3072];
  float mn = fminf(fminf(v0, v1), fminf(v2, v3));
  float mx = fmaxf(fmaxf(v0, v1), fmaxf(v2, v3));
  __shared__ float rmn[1024], rmx[1024];
  rmn[tid] = mn; rmx[tid] = mx;
  __syncthreads();
  for (int s = 512; s > 0; s >>= 1) {
    if (tid < s) {
      rmn[tid] = fminf(rmn[tid], rmn[tid + s]);
      rmx[tid] = fmaxf(rmx[tid], rmx[tid + s]);
    }
    __syncthreads();
  }
  float lo = rmn[0];
  float denom = rmx[0] - rmn[0] + 1e-6f;
  gate[tid]        = (v0 - lo) / denom;
  gate[tid + 1024] = (v1 - lo) / denom;
  gate[tid + 2048] = (v2 - lo) / denom;
  gate[tid + 3072] = (v3 - lo) / denom;
}

// ---------------------------------------------------------------------------
// K3a: spectral PE conv path -> pe2 [64][4096]
// ---------------------------------------------------------------------------
__global__ void k_pe(const float* __restrict__ omega,
                     const float* __restrict__ w1, const float* __restrict__ b1,
                     const float* __restrict__ w2, const float* __restrict__ b2,
                     float* __restrict__ pe2) {
  int n = blockIdx.x;
  int j = threadIdx.x;  // 64
  __shared__ float pec[3][64];
  __shared__ float hs[128];
  for (int t = 0; t < 3; ++t) {
    int m = n + t - 1;
    float v = 0.f;
    if (m >= 0 && m < NN) {
      int l1 = m >> 6, l2 = m & 63;
      float rel = (float)(l1 - l2);
      v = (j < 32) ? sinf(rel * omega[j]) : cosf(rel * omega[j - 32]);
    }
    pec[t][j] = v;
  }
  __syncthreads();
  for (int o = j; o < 128; o += 64) {
    int ci = o >> 1;
    float hv = b1[o];
    #pragma unroll
    for (int t = 0; t < 3; ++t) hv += pec[t][ci] * w1[o * 3 + t];
    hv = 0.5f * hv * (1.f + erff(hv * 0.70710678118654752f));
    hs[o] = hv;
  }
  __syncthreads();
  float acc = b2[j];
  for (int o = 0; o < 128; ++o) acc += hs[o] * w2[j * 128 + o];
  pe2[(size_t)j * NN + n] = acc;
}

// ---------------------------------------------------------------------------
// K3b: channel means -> sigmoid gate gpe[64]
// ---------------------------------------------------------------------------
__global__ void k_gatepe(const float* __restrict__ pe2,
                         const float* __restrict__ wg, const float* __restrict__ bg,
                         float* __restrict__ gpe) {
  int tid = threadIdx.x;  // 256
  int j = tid & 63, part = tid >> 6;
  float s = 0.f;
  const float* row = pe2 + (size_t)j * NN + part * 1024;
  for (int t = 0; t < 1024; ++t) s += row[t];
  __shared__ float ps[4][64];
  __shared__ float mean[64];
  ps[part][j] = s;
  __syncthreads();
  if (tid < 64) mean[j] = (ps[0][j] + ps[1][j] + ps[2][j] + ps[3][j]) * (1.f / 4096.f);
  __syncthreads();
  if (tid < 64) {
    float g = bg[j];
    for (int k2 = 0; k2 < 64; ++k2) g += wg[j * 64 + k2] * mean[k2];
    gpe[j] = 1.f / (1.f + expf(-g));
  }
}

// ---------------------------------------------------------------------------
// K3c: rope multiplier
// ---------------------------------------------------------------------------
__global__ void k_ropemul(const float* __restrict__ pe2, const float* __restrict__ gpe,
                          float* __restrict__ ropem) {
  int idx = blockIdx.x * 256 + threadIdx.x;
  int n = idx >> 6, dd = idx & 63;
  ropem[idx] = 1.f + pe2[(size_t)dd * NN + n] * gpe[n >> 6] * 0.35355339059327373f;
}

// ---------------------------------------------------------------------------
// Prep: A = x*gate -> bf16 hi/lo split
// ---------------------------------------------------------------------------
__global__ void k_prep_a(const float* __restrict__ x, const float* __restrict__ gate,
                         ushort* __restrict__ Ah, ushort* __restrict__ Al) {
  int idx4 = (blockIdx.x * 256 + threadIdx.x) * 4;
  int row = idx4 >> 9;
  float g = gate[row & (NN - 1)];
  float4 v = *(const float4*)&x[idx4];
  float vv[4] = {v.x * g, v.y * g, v.z * g, v.w * g};
  ushort4 ah, al;
  ushort* ap = (ushort*)&ah;
  ushort* lp = (ushort*)&al;
  #pragma unroll
  for (int i = 0; i < 4; ++i) {
    ap[i] = f2b(vv[i]);
    lp[i] = f2b(vv[i] - b2f(ap[i]));
  }
  *(ushort4*)&Ah[idx4] = ah;
  *(ushort4*)&Al[idx4] = al;
}

// Prep: f32 -> bf16 (hi only; B-side of 2-term GEMM)
__global__ void k_prep_h(const float* __restrict__ src,
                         ushort* __restrict__ Sh, int nelem) {
  int idx4 = (blockIdx.x * 256 + threadIdx.x) * 4;
  if (idx4 >= nelem) return;
  float4 v = *(const float4*)&src[idx4];
  ushort4 h;
  ((ushort*)&h)[0] = f2b(v.x);
  ((ushort*)&h)[1] = f2b(v.y);
  ((ushort*)&h)[2] = f2b(v.z);
  ((ushort*)&h)[3] = f2b(v.w);
  *(ushort4*)&Sh[idx4] = h;
}

// ---------------------------------------------------------------------------
// 2-term bf16 MFMA GEMM: C = (Ah+Al)[M][512] * Bh[ncols][512]^T (+bias)
// 128x128 tile, BK=32, 4 waves (2x2), 16x16x32 MFMA, XOR bank swizzle,
// XCD-aware 1-D grid swizzle. EPI=0: f32 out. EPI=1: qkv epilogue.
// ---------------------------------------------------------------------------
template <int EPI>
__global__ __launch_bounds__(256) void k_gemm3(
    const ushort* __restrict__ Agh, const ushort* __restrict__ Agl,
    const ushort* __restrict__ Bgh,
    const float* __restrict__ bias, const float* __restrict__ ropem,
    float* __restrict__ outF, ushort* __restrict__ qb, ushort* __restrict__ kb,
    ushort* __restrict__ vb, int ntn, int ncols) {
  // XCD-aware swizzle (grid % 8 == 0): each XCD gets contiguous logical chunk
  const int nwg = gridDim.x;
  const int hw = blockIdx.x;
  const int logical = (hw & 7) * (nwg >> 3) + (hw >> 3);
  const int m0 = (logical / ntn) * 128, n0 = (logical % ntn) * 128;

  const int tid = threadIdx.x, wave = tid >> 6, lane = tid & 63;
  const int wm = wave >> 1, wn = wave & 1;
  __shared__ ushort sAh[4096], sAl[4096], sBh[4096];  // [128][32] each, swizzled
  f32x4 acc[4][4] = {};

  // staging: lane -> row lr = lane>>2, dest unit ci = lane&3; source col swizzled
  const int lr = lane >> 2;
  const int ci = lane & 3;
  const int scol = (ci ^ ((lr >> 1) & 3)) * 8;  // inverse-swizzled global source

  // read-side swizzle
  const int rA = lane & 15;
  const int cswz = ((lane >> 4) ^ ((rA >> 1) & 3)) * 8;

  for (int k0 = 0; k0 < CC; k0 += 32) {
    #pragma unroll
    for (int j = 0; j < 2; ++j) {
      int chunk = wave * 2 + j;  // wave-uniform
      int row = chunk * 16 + lr;
      size_t ga = (size_t)(m0 + row) * CC + k0 + scol;
      size_t gb = (size_t)(n0 + row) * CC + k0 + scol;
      gload16(Agh + ga, sAh + chunk * 512);
      gload16(Agl + ga, sAl + chunk * 512);
      gload16(Bgh + gb, sBh + chunk * 512);
    }
    __syncthreads();
    bf16x8 ah[4], alo[4], bh[4];
    #pragma unroll
    for (int m = 0; m < 4; ++m) {
      int off = (wm * 64 + m * 16 + rA) * 32 + cswz;
      ah[m] = *(const bf16x8*)(sAh + off);
      alo[m] = *(const bf16x8*)(sAl + off);
    }
    #pragma unroll
    for (int n = 0; n < 4; ++n) {
      int off = (wn * 64 + n * 16 + rA) * 32 + cswz;
      bh[n] = *(const bf16x8*)(sBh + off);
    }
    #pragma unroll
    for (int m = 0; m < 4; ++m)
      #pragma unroll
      for (int n = 0; n < 4; ++n) {
        acc[m][n] = __builtin_amdgcn_mfma_f32_16x16x32_bf16(ah[m], bh[n], acc[m][n], 0, 0, 0);
        acc[m][n] = __builtin_amdgcn_mfma_f32_16x16x32_bf16(alo[m], bh[n], acc[m][n], 0, 0, 0);
      }
    __syncthreads();
  }

  #pragma unroll
  for (int m = 0; m < 4; ++m) {
    #pragma unroll
    for (int n = 0; n < 4; ++n) {
      #pragma unroll
      for (int r = 0; r < 4; ++r) {
        int row = m0 + wm * 64 + m * 16 + (lane >> 4) * 4 + r;
        int col = n0 + wn * 64 + n * 16 + (lane & 15);
        float val = acc[m][n][r] + bias[col];
        if (EPI == 0) {
          outF[(size_t)row * ncols + col] = val;
        } else {
          int nseq = row & (NN - 1), b = row >> 12;
          int part = col >> 9, c = col & 511, h = c >> 6, dd = c & 63;
          size_t oi = (((size_t)b * HH + h) * NN + nseq) * DD + dd;
          if (part == 2) {
            vb[oi] = f2b(val);
          } else {
            float e = val > 0.f ? val + 1.f : expf(val);  // elu+1
            float res = e * ropem[nseq * 64 + dd];
            (part == 0 ? qb : kb)[oi] = f2b(res);
          }
        }
      }
    }
  }
}

// ---------------------------------------------------------------------------
// K5a: ctx partials (bf16 q/k, f32 accum)
// ---------------------------------------------------------------------------
__global__ __launch_bounds__(256) void k_ctx_part(
    const ushort* __restrict__ qb, const ushort* __restrict__ kb,
    float* __restrict__ ctxp) {
  int bh = blockIdx.x >> 4;
  int chunk = blockIdx.x & 15;
  const int tx = threadIdx.x, ty = threadIdx.y, tid = ty * 16 + tx;
  __shared__ float Qs[16][68], Ks[16][68];
  float acc[4][4] = {};
  const size_t base = (size_t)bh * NN * DD;
  for (int n0 = chunk * 256; n0 < chunk * 256 + 256; n0 += 16) {
    int idx4 = tid * 4;
    int nl = idx4 >> 6, dd = idx4 & 63;
    ushort4 qv = *(const ushort4*)&qb[base + (size_t)(n0 + nl) * DD + dd];
    ushort4 kv = *(const ushort4*)&kb[base + (size_t)(n0 + nl) * DD + dd];
    Qs[nl][dd] = b2f(qv.x); Qs[nl][dd + 1] = b2f(qv.y);
    Qs[nl][dd + 2] = b2f(qv.z); Qs[nl][dd + 3] = b2f(qv.w);
    Ks[nl][dd] = b2f(kv.x); Ks[nl][dd + 1] = b2f(kv.y);
    Ks[nl][dd + 2] = b2f(kv.z); Ks[nl][dd + 3] = b2f(kv.w);
    __syncthreads();
    #pragma unroll
    for (int nn2 = 0; nn2 < 16; ++nn2) {
      float a[4], bv[4];
      #pragma unroll
      for (int i = 0; i < 4; ++i) a[i] = Qs[nn2][ty + 16 * i];
      #pragma unroll
      for (int j = 0; j < 4; ++j) bv[j] = Ks[nn2][tx + 16 * j];
      #pragma unroll
      for (int i = 0; i < 4; ++i)
        #pragma unroll
        for (int j = 0; j < 4; ++j) acc[i][j] += a[i] * bv[j];
    }
    __syncthreads();
  }
  const float scale = 1.f / 512.f;
  #pragma unroll
  for (int i = 0; i < 4; ++i)
    #pragma unroll
    for (int j = 0; j < 4; ++j)
      ctxp[(size_t)(bh * 16 + chunk) * 4096 + (ty + 16 * i) * 64 + (tx + 16 * j)] =
          acc[i][j] * scale;
}

// K5b: deterministic reduce
__global__ void k_ctx_red(const float* __restrict__ ctxp, float* __restrict__ ctx) {
  int bh = blockIdx.x;
  int tid = threadIdx.x;
  for (int r = 0; r < 16; ++r) {
    int idx = tid + 256 * r;
    float s = 0.f;
    for (int c2 = 0; c2 < 16; ++c2) s += ctxp[(size_t)(bh * 16 + c2) * 4096 + idx];
    ctx[(size_t)bh * 4096 + idx] = s;
  }
}

// ---------------------------------------------------------------------------
// K6: out[n,e] = scale * sum_d v[n,d]*ctx[d,e]; write bf16 hi/lo [B*N, C]
// ---------------------------------------------------------------------------
__global__ __launch_bounds__(256) void k_out(
    const ushort* __restrict__ vb, const float* __restrict__ ctx,
    ushort* __restrict__ Aoh, ushort* __restrict__ Aol) {
  int bh = blockIdx.x >> 6;
  int t = blockIdx.x & 63;
  int b = bh >> 3, h = bh & 7;
  const int tx = threadIdx.x, ty = threadIdx.y, tid = ty * 16 + tx;
  __shared__ float Vs[64][68], Cs[64][68];
  #pragma unroll
  for (int it = 0; it < 4; ++it) {
    int idx4 = (tid + 256 * it) * 4;
    int r = idx4 >> 6, cc = idx4 & 63;
    *(float4*)&Cs[r][cc] = *(const float4*)&ctx[(size_t)bh * 4096 + idx4];
    ushort4 vv = *(const ushort4*)&vb[((size_t)bh * NN + t * 64 + r) * DD + cc];
    Vs[r][cc] = b2f(vv.x); Vs[r][cc + 1] = b2f(vv.y);
    Vs[r][cc + 2] = b2f(vv.z); Vs[r][cc + 3] = b2f(vv.w);
  }
  __syncthreads();
  float acc[4][4] = {};
  for (int d2 = 0; d2 < 64; ++d2) {
    float a[4], bv[4];
    #pragma unroll
    for (int i = 0; i < 4; ++i) a[i] = Vs[ty + 16 * i][d2];
    #pragma unroll
    for (int j = 0; j < 4; ++j) bv[j] = Cs[d2][tx + 16 * j];
    #pragma unroll
    for (int i = 0; i < 4; ++i)
      #pragma unroll
      for (int j = 0; j < 4; ++j) acc[i][j] += a[i] * bv[j];
  }
  const float scale = 1.f / 512.f;
  #pragma unroll
  for (int i = 0; i < 4; ++i)
    #pragma unroll
    for (int j = 0; j < 4; ++j) {
      size_t idx = ((size_t)b * NN + t * 64 + ty + 16 * i) * CC + h * 64 + tx + 16 * j;
      float val = acc[i][j] * scale;
      ushort hi = f2b(val);
      Aoh[idx] = hi;
      Aol[idx] = f2b(val - b2f(hi));
    }
}

// ---------------------------------------------------------------------------
extern "C" void kernel_launch(void* const* d_in, const int* in_sizes, int n_in,
                              void* d_out, int out_size, void* d_ws, size_t ws_size,
                              hipStream_t stream) {
  const float* x    = (const float*)d_in[0];
  const float* lpw  = (const float*)d_in[1];
  const float* lvw  = (const float*)d_in[2];
  const float* wqkv = (const float*)d_in[3];
  const float* bqkv = (const float*)d_in[4];
  const float* wproj= (const float*)d_in[5];
  const float* bproj= (const float*)d_in[6];
  const float* omega= (const float*)d_in[7];
  const float* w1   = (const float*)d_in[8];
  const float* b1   = (const float*)d_in[9];
  const float* w2   = (const float*)d_in[10];
  const float* b2   = (const float*)d_in[11];
  const float* wg   = (const float*)d_in[12];
  const float* bg   = (const float*)d_in[13];
  float* out = (float*)d_out;

  constexpr size_t MB = 1024 * 1024;
  char* w = (char*)d_ws;
  int*   peak   = (int*)(w);
  int*   valley = (int*)(w + 16 * 1024);
  float* attn   = (float*)(w + 32 * 1024);
  float* gate   = (float*)(w + 48 * 1024);
  float* pe2    = (float*)(w + 64 * 1024);        // 1 MiB
  float* gpe    = (float*)(w + 1088 * 1024);
  float* ropem  = (float*)(w + 1152 * 1024);      // 1 MiB
  ushort* qb    = (ushort*)(w + 4 * MB);          // 16 MiB bf16 [B,H,N,D]
  ushort* kb    = (ushort*)(w + 20 * MB);         // 16 MiB
  ushort* vb    = (ushort*)(w + 36 * MB);         // 16 MiB bf16 [B,H,N,D]
  ushort* Ah    = (ushort*)(w + 52 * MB);         // 16 MiB
  ushort* Al    = (ushort*)(w + 68 * MB);         // 16 MiB
  ushort* Wh    = (ushort*)(w + 84 * MB);         // 1.5 MiB
  ushort* Ph    = (ushort*)(w + 86 * MB);         // 0.5 MiB
  float* ctxp   = (float*)(w + 87 * MB);          // 8 MiB
  float* ctx    = (float*)(w + 95 * MB);          // 0.5 MiB -> end 95.5 MiB
  // aliases (stream-ordered reuse):
  ushort* Aoh = Ah;                                // Ah dead after qkv gemm
  ushort* Aol = Al;                                // Al dead after qkv gemm

  hipMemsetAsync(peak, 0, 2 * 4096 * sizeof(int), stream);

  k_counts<<<BB * 64, 512, 0, stream>>>(x, peak, valley);
  k_gsum<<<NN, 256, 0, stream>>>(peak, valley, lpw, lvw, attn);
  k_norm<<<1, 1024, 0, stream>>>(attn, gate);
  k_pe<<<NN, 64, 0, stream>>>(omega, w1, b1, w2, b2, pe2);
  k_gatepe<<<1, 256, 0, stream>>>(pe2, wg, bg, gpe);
  k_ropemul<<<1024, 256, 0, stream>>>(pe2, gpe, ropem);

  k_prep_a<<<8192, 256, 0, stream>>>(x, gate, Ah, Al);
  k_prep_h<<<768, 256, 0, stream>>>(wqkv, Wh, 3 * CC * CC);
  k_prep_h<<<256, 256, 0, stream>>>(wproj, Ph, CC * CC);

  // qkv: M=16384, N=1536 -> 12*128 = 1536 blocks (1-D, XCD-swizzled)
  k_gemm3<1><<<1536, 256, 0, stream>>>(Ah, Al, Wh, bqkv, ropem,
                                       nullptr, qb, kb, vb, 12, 0);
  k_ctx_part<<<512, dim3(16, 16), 0, stream>>>(qb, kb, ctxp);
  k_ctx_red<<<32, 256, 0, stream>>>(ctxp, ctx);
  k_out<<<2048, dim3(16, 16), 0, stream>>>(vb, ctx, Aoh, Aol);

  // proj: M=16384, N=512 -> 4*128 = 512 blocks
  k_gemm3<0><<<512, 256, 0, stream>>>(Aoh, Aol, Ph, bproj, nullptr,
                                      out, nullptr, nullptr, nullptr, 4, CC);
}

// Round 4
// 254.706 us; speedup vs baseline: 3.0552x; 1.1424x over previous
//
#include <hip/hip_runtime.h>
#include <hip/hip_bf16.h>
#include <math.h>

constexpr int BB = 4;
constexpr int NN = 4096;
constexpr int CC = 512;
constexpr int HH = 8;
constexpr int DD = 64;
constexpr int NCNT = NN - 2;

typedef __bf16 bf16x8 __attribute__((ext_vector_type(8)));
typedef float f32x4 __attribute__((ext_vector_type(4)));

__device__ __forceinline__ float b2f(ushort u) {
  unsigned v = ((unsigned)u) << 16;
  return __builtin_bit_cast(float, v);
}
__device__ __forceinline__ ushort f2b(float f) {
  __hip_bfloat16 h = __float2bfloat16(f);
  return __builtin_bit_cast(ushort, h);
}
__device__ __forceinline__ void gload16(const ushort* g, ushort* l) {
  __builtin_amdgcn_global_load_lds(
      (const __attribute__((address_space(1))) unsigned int*)g,
      (__attribute__((address_space(3))) unsigned int*)l, 16, 0, 0);
}

// ---------------------------------------------------------------------------
// K1: second-difference sign counts
// ---------------------------------------------------------------------------
__global__ void k_counts(const float* __restrict__ x,
                         int* __restrict__ peak, int* __restrict__ valley) {
  int b = blockIdx.x >> 6;
  int tile = blockIdx.x & 63;
  int c = threadIdx.x;
  int lane = threadIdx.x & 63;
  for (int ii = 0; ii < 64; ++ii) {
    int i = tile * 64 + ii;
    if (i >= NCNT) break;
    const float* xp = x + ((size_t)b * NN + i) * CC + c;
    float x0 = xp[0], x1 = xp[CC], x2 = xp[2 * CC];
    float d2 = (x2 - x1) - (x1 - x0);
    unsigned long long mneg = __ballot(d2 < 0.0f);
    unsigned long long mpos = __ballot(d2 > 0.0f);
    if (lane == 0) {
      atomicAdd(&peak[i], __popcll(mneg));
      atomicAdd(&valley[i], __popcll(mpos));
    }
  }
}

// ---------------------------------------------------------------------------
// K2a: Gaussian sums
// ---------------------------------------------------------------------------
__global__ void k_gsum(const int* __restrict__ peak, const int* __restrict__ valley,
                       const float* __restrict__ lpw, const float* __restrict__ lvw,
                       float* __restrict__ attn) {
  int p = blockIdx.x;
  int tid = threadIdx.x;
  float ipw = expf(-lpw[0]);
  float ivw = expf(-lvw[0]);
  float acc = 0.f;
  for (int i = tid; i < NCNT; i += 256) {
    float dd = (float)(p - (i + 1));
    float t1 = dd * ipw;
    float t2 = dd * ivw;
    acc += (float)peak[i] * expf(-t1 * t1) + (float)valley[i] * expf(-t2 * t2);
  }
  __shared__ float red[256];
  red[tid] = acc;
  __syncthreads();
  for (int s = 128; s > 0; s >>= 1) {
    if (tid < s) red[tid] += red[tid + s];
    __syncthreads();
  }
  if (tid == 0) attn[p] = red[0];
}

// ---------------------------------------------------------------------------
// K2b: min-max normalize
// ---------------------------------------------------------------------------
__global__ void k_norm(const float* __restrict__ attn, float* __restrict__ gate) {
  int tid = threadIdx.x;  // 1024
  float v0 = attn[tid], v1 = attn[tid + 1024], v2 = attn[tid + 2048], v3 = attn[tid + 3072];
  float mn = fminf(fminf(v0, v1), fminf(v2, v3));
  float mx = fmaxf(fmaxf(v0, v1), fmaxf(v2, v3));
  __shared__ float rmn[1024], rmx[1024];
  rmn[tid] = mn; rmx[tid] = mx;
  __syncthreads();
  for (int s = 512; s > 0; s >>= 1) {
    if (tid < s) {
      rmn[tid] = fminf(rmn[tid], rmn[tid + s]);
      rmx[tid] = fmaxf(rmx[tid], rmx[tid + s]);
    }
    __syncthreads();
  }
  float lo = rmn[0];
  float denom = rmx[0] - rmn[0] + 1e-6f;
  gate[tid]        = (v0 - lo) / denom;
  gate[tid + 1024] = (v1 - lo) / denom;
  gate[tid + 2048] = (v2 - lo) / denom;
  gate[tid + 3072] = (v3 - lo) / denom;
}

// ---------------------------------------------------------------------------
// K3a: spectral PE conv path -> pe2 [64][4096]
// ---------------------------------------------------------------------------
__global__ void k_pe(const float* __restrict__ omega,
                     const float* __restrict__ w1, const float* __restrict__ b1,
                     const float* __restrict__ w2, const float* __restrict__ b2,
                     float* __restrict__ pe2) {
  int n = blockIdx.x;
  int j = threadIdx.x;  // 64
  __shared__ float pec[3][64];
  __shared__ float hs[128];
  for (int t = 0; t < 3; ++t) {
    int m = n + t - 1;
    float v = 0.f;
    if (m >= 0 && m < NN) {
      int l1 = m >> 6, l2 = m & 63;
      float rel = (float)(l1 - l2);
      v = (j < 32) ? sinf(rel * omega[j]) : cosf(rel * omega[j - 32]);
    }
    pec[t][j] = v;
  }
  __syncthreads();
  for (int o = j; o < 128; o += 64) {
    int ci = o >> 1;
    float hv = b1[o];
    #pragma unroll
    for (int t = 0; t < 3; ++t) hv += pec[t][ci] * w1[o * 3 + t];
    hv = 0.5f * hv * (1.f + erff(hv * 0.70710678118654752f));
    hs[o] = hv;
  }
  __syncthreads();
  float acc = b2[j];
  for (int o = 0; o < 128; ++o) acc += hs[o] * w2[j * 128 + o];
  pe2[(size_t)j * NN + n] = acc;
}

// ---------------------------------------------------------------------------
// K3b: channel means -> sigmoid gate gpe[64]
// ---------------------------------------------------------------------------
__global__ void k_gatepe(const float* __restrict__ pe2,
                         const float* __restrict__ wg, const float* __restrict__ bg,
                         float* __restrict__ gpe) {
  int tid = threadIdx.x;  // 256
  int j = tid & 63, part = tid >> 6;
  float s = 0.f;
  const float* row = pe2 + (size_t)j * NN + part * 1024;
  for (int t = 0; t < 1024; ++t) s += row[t];
  __shared__ float ps[4][64];
  __shared__ float mean[64];
  ps[part][j] = s;
  __syncthreads();
  if (tid < 64) mean[j] = (ps[0][j] + ps[1][j] + ps[2][j] + ps[3][j]) * (1.f / 4096.f);
  __syncthreads();
  if (tid < 64) {
    float g = bg[j];
    for (int k2 = 0; k2 < 64; ++k2) g += wg[j * 64 + k2] * mean[k2];
    gpe[j] = 1.f / (1.f + expf(-g));
  }
}

// ---------------------------------------------------------------------------
// K3c: rope multiplier  ropem[n*64+dd] = 1 + pe2[dd,n]*gpe[n>>6]*64^-0.25
// ---------------------------------------------------------------------------
__global__ void k_ropemul(const float* __restrict__ pe2, const float* __restrict__ gpe,
                          float* __restrict__ ropem) {
  int idx = blockIdx.x * 256 + threadIdx.x;
  int n = idx >> 6, dd = idx & 63;
  ropem[idx] = 1.f + pe2[(size_t)dd * NN + n] * gpe[n >> 6] * 0.35355339059327373f;
}

// ---------------------------------------------------------------------------
// Prep: x -> bf16 (gate moved to GEMM epilogue by linearity)
// ---------------------------------------------------------------------------
__global__ void k_prep_x(const float* __restrict__ x, ushort* __restrict__ Xh) {
  int idx4 = (blockIdx.x * 256 + threadIdx.x) * 4;
  float4 v = *(const float4*)&x[idx4];
  ushort4 h;
  ((ushort*)&h)[0] = f2b(v.x);
  ((ushort*)&h)[1] = f2b(v.y);
  ((ushort*)&h)[2] = f2b(v.z);
  ((ushort*)&h)[3] = f2b(v.w);
  *(ushort4*)&Xh[idx4] = h;
}

// Prep: f32 -> bf16 (weights)
__global__ void k_prep_h(const float* __restrict__ src,
                         ushort* __restrict__ Sh, int nelem) {
  int idx4 = (blockIdx.x * 256 + threadIdx.x) * 4;
  if (idx4 >= nelem) return;
  float4 v = *(const float4*)&src[idx4];
  ushort4 h;
  ((ushort*)&h)[0] = f2b(v.x);
  ((ushort*)&h)[1] = f2b(v.y);
  ((ushort*)&h)[2] = f2b(v.z);
  ((ushort*)&h)[3] = f2b(v.w);
  *(ushort4*)&Sh[idx4] = h;
}

// ---------------------------------------------------------------------------
// 2-phase double-buffered bf16 MFMA GEMM.
// TERMS=1: C = A*B^T.  TERMS=2: C = (Ah+Al)*B^T.
// 128x128 tile, BK=32, 4 waves (2x2), XOR bank swizzle, XCD grid swizzle.
// EPI=0: f32 out (+bias). EPI=1: qkv epilogue (gate*acc+bias, elu+1, rope,
//   q/k/v -> bf16 [B,H,N,D]).
// ---------------------------------------------------------------------------
template <int TERMS, int EPI>
__global__ __launch_bounds__(256) void k_gemm2(
    const ushort* __restrict__ Agh, const ushort* __restrict__ Agl,
    const ushort* __restrict__ Bgh,
    const float* __restrict__ bias, const float* __restrict__ gate,
    const float* __restrict__ ropem,
    float* __restrict__ outF, ushort* __restrict__ qb, ushort* __restrict__ kb,
    ushort* __restrict__ vb, int ntn, int ncols) {
  const int nwg = gridDim.x;
  const int hw = blockIdx.x;
  const int logical = (hw & 7) * (nwg >> 3) + (hw >> 3);
  const int m0 = (logical / ntn) * 128, n0 = (logical % ntn) * 128;

  const int tid = threadIdx.x, wave = tid >> 6, lane = tid & 63;
  const int wm = wave >> 1, wn = wave & 1;
  __shared__ ushort sA[2][TERMS][4096];
  __shared__ ushort sB[2][4096];
  f32x4 acc[4][4] = {};

  const int lr = lane >> 2;
  const int ci = lane & 3;
  const int scol = (ci ^ ((lr >> 1) & 3)) * 8;   // inverse-swizzled source col
  const int rA = lane & 15;
  const int cswz = ((lane >> 4) ^ ((rA >> 1) & 3)) * 8;  // read-side swizzle

  const int chunk0 = wave * 2, chunk1 = wave * 2 + 1;
  const int row0 = chunk0 * 16 + lr, row1 = chunk1 * 16 + lr;

  // prologue: stage k0=0 into buf 0
  {
    size_t ga0 = (size_t)(m0 + row0) * CC + scol;
    size_t ga1 = (size_t)(m0 + row1) * CC + scol;
    size_t gb0 = (size_t)(n0 + row0) * CC + scol;
    size_t gb1 = (size_t)(n0 + row1) * CC + scol;
    gload16(Agh + ga0, &sA[0][0][chunk0 * 512]);
    gload16(Agh + ga1, &sA[0][0][chunk1 * 512]);
    if (TERMS == 2) {
      gload16(Agl + ga0, &sA[0][1][chunk0 * 512]);
      gload16(Agl + ga1, &sA[0][1][chunk1 * 512]);
    }
    gload16(Bgh + gb0, &sB[0][chunk0 * 512]);
    gload16(Bgh + gb1, &sB[0][chunk1 * 512]);
  }
  __syncthreads();

  int cur = 0;
  for (int t = 0; t < 16; ++t) {
    // stage next tile into buf cur^1 (issue early; latency hides under MFMA)
    if (t < 15) {
      int k0 = (t + 1) * 32;
      size_t ga0 = (size_t)(m0 + row0) * CC + k0 + scol;
      size_t ga1 = (size_t)(m0 + row1) * CC + k0 + scol;
      size_t gb0 = (size_t)(n0 + row0) * CC + k0 + scol;
      size_t gb1 = (size_t)(n0 + row1) * CC + k0 + scol;
      int nxt = cur ^ 1;
      gload16(Agh + ga0, &sA[nxt][0][chunk0 * 512]);
      gload16(Agh + ga1, &sA[nxt][0][chunk1 * 512]);
      if (TERMS == 2) {
        gload16(Agl + ga0, &sA[nxt][1][chunk0 * 512]);
        gload16(Agl + ga1, &sA[nxt][1][chunk1 * 512]);
      }
      gload16(Bgh + gb0, &sB[nxt][chunk0 * 512]);
      gload16(Bgh + gb1, &sB[nxt][chunk1 * 512]);
    }
    // fragments from buf cur
    bf16x8 a0[4], a1[4], bfr[4];
    #pragma unroll
    for (int m = 0; m < 4; ++m) {
      int off = (wm * 64 + m * 16 + rA) * 32 + cswz;
      a0[m] = *(const bf16x8*)(&sA[cur][0][off]);
      if (TERMS == 2) a1[m] = *(const bf16x8*)(&sA[cur][1][off]);
    }
    #pragma unroll
    for (int n = 0; n < 4; ++n) {
      int off = (wn * 64 + n * 16 + rA) * 32 + cswz;
      bfr[n] = *(const bf16x8*)(&sB[cur][off]);
    }
    __builtin_amdgcn_s_setprio(1);
    #pragma unroll
    for (int m = 0; m < 4; ++m)
      #pragma unroll
      for (int n = 0; n < 4; ++n) {
        acc[m][n] = __builtin_amdgcn_mfma_f32_16x16x32_bf16(a0[m], bfr[n], acc[m][n], 0, 0, 0);
        if (TERMS == 2)
          acc[m][n] = __builtin_amdgcn_mfma_f32_16x16x32_bf16(a1[m], bfr[n], acc[m][n], 0, 0, 0);
      }
    __builtin_amdgcn_s_setprio(0);
    __syncthreads();  // drains vmcnt(0): next tile staged; lgkm done
    cur ^= 1;
  }

  #pragma unroll
  for (int m = 0; m < 4; ++m) {
    #pragma unroll
    for (int n = 0; n < 4; ++n) {
      #pragma unroll
      for (int r = 0; r < 4; ++r) {
        int row = m0 + wm * 64 + m * 16 + (lane >> 4) * 4 + r;
        int col = n0 + wn * 64 + n * 16 + (lane & 15);
        if (EPI == 0) {
          float val = acc[m][n][r] + bias[col];
          outF[(size_t)row * ncols + col] = val;
        } else {
          int nseq = row & (NN - 1), b = row >> 12;
          float val = acc[m][n][r] * gate[nseq] + bias[col];
          int part = col >> 9, c = col & 511, h = c >> 6, dd = c & 63;
          size_t oi = (((size_t)b * HH + h) * NN + nseq) * DD + dd;
          if (part == 2) {
            vb[oi] = f2b(val);
          } else {
            float e = val > 0.f ? val + 1.f : expf(val);  // elu+1
            float res = e * ropem[nseq * 64 + dd];
            (part == 0 ? qb : kb)[oi] = f2b(res);
          }
        }
      }
    }
  }
}

// ---------------------------------------------------------------------------
// K5a: ctx partials. Thread owns contiguous 4x4 (d,e) patch -> float4 LDS reads.
// ---------------------------------------------------------------------------
__global__ __launch_bounds__(256) void k_ctx_part(
    const ushort* __restrict__ qb, const ushort* __restrict__ kb,
    float* __restrict__ ctxp) {
  int bh = blockIdx.x >> 4;
  int chunk = blockIdx.x & 15;
  const int tid = threadIdx.x;
  const int td = tid >> 4;   // d-quad: rows td*4..+3
  const int te = tid & 15;   // e-quad: cols te*4..+3
  __shared__ float Qs[16][68], Ks[16][68];
  float acc[4][4] = {};
  const size_t base = (size_t)bh * NN * DD;
  for (int n0 = chunk * 256; n0 < chunk * 256 + 256; n0 += 16) {
    int idx4 = tid * 4;
    int nl = idx4 >> 6, dd = idx4 & 63;
    ushort4 qv = *(const ushort4*)&qb[base + (size_t)(n0 + nl) * DD + dd];
    ushort4 kv = *(const ushort4*)&kb[base + (size_t)(n0 + nl) * DD + dd];
    Qs[nl][dd] = b2f(qv.x); Qs[nl][dd + 1] = b2f(qv.y);
    Qs[nl][dd + 2] = b2f(qv.z); Qs[nl][dd + 3] = b2f(qv.w);
    Ks[nl][dd] = b2f(kv.x); Ks[nl][dd + 1] = b2f(kv.y);
    Ks[nl][dd + 2] = b2f(kv.z); Ks[nl][dd + 3] = b2f(kv.w);
    __syncthreads();
    #pragma unroll
    for (int nn2 = 0; nn2 < 16; ++nn2) {
      float4 a = *(const float4*)&Qs[nn2][td * 4];   // broadcast across 16 lanes
      float4 bv = *(const float4*)&Ks[nn2][te * 4];  // 2-way, free
      float aa[4] = {a.x, a.y, a.z, a.w};
      float bb[4] = {bv.x, bv.y, bv.z, bv.w};
      #pragma unroll
      for (int i = 0; i < 4; ++i)
        #pragma unroll
        for (int j = 0; j < 4; ++j) acc[i][j] += aa[i] * bb[j];
    }
    __syncthreads();
  }
  const float scale = 1.f / 512.f;
  #pragma unroll
  for (int i = 0; i < 4; ++i)
    #pragma unroll
    for (int j = 0; j < 4; ++j)
      ctxp[(size_t)(bh * 16 + chunk) * 4096 + (td * 4 + i) * 64 + (te * 4 + j)] =
          acc[i][j] * scale;
}

// K5b: deterministic reduce
__global__ void k_ctx_red(const float* __restrict__ ctxp, float* __restrict__ ctx) {
  int bh = blockIdx.x;
  int tid = threadIdx.x;
  for (int r = 0; r < 16; ++r) {
    int idx = tid + 256 * r;
    float s = 0.f;
    for (int c2 = 0; c2 < 16; ++c2) s += ctxp[(size_t)(bh * 16 + c2) * 4096 + idx];
    ctx[(size_t)bh * 4096 + idx] = s;
  }
}

// ---------------------------------------------------------------------------
// K6: out[n,e] = scale * sum_d v[n,d]*ctx[d,e]; bf16 hi/lo out [B*N, C].
// Thread owns contiguous 4x4 (n,e) patch.
// ---------------------------------------------------------------------------
__global__ __launch_bounds__(256) void k_out(
    const ushort* __restrict__ vb, const float* __restrict__ ctx,
    ushort* __restrict__ Aoh, ushort* __restrict__ Aol) {
  int bh = blockIdx.x >> 6;
  int t = blockIdx.x & 63;
  int b = bh >> 3, h = bh & 7;
  const int tid = threadIdx.x;
  const int tn = tid >> 4;   // n-quad
  const int te = tid & 15;   // e-quad
  __shared__ float Vs[64][68], Cs[64][68];
  #pragma unroll
  for (int it = 0; it < 4; ++it) {
    int idx4 = (tid + 256 * it) * 4;
    int r = idx4 >> 6, cc = idx4 & 63;
    *(float4*)&Cs[r][cc] = *(const float4*)&ctx[(size_t)bh * 4096 + idx4];
    ushort4 vv = *(const ushort4*)&vb[((size_t)bh * NN + t * 64 + r) * DD + cc];
    Vs[r][cc] = b2f(vv.x); Vs[r][cc + 1] = b2f(vv.y);
    Vs[r][cc + 2] = b2f(vv.z); Vs[r][cc + 3] = b2f(vv.w);
  }
  __syncthreads();
  float acc[4][4] = {};
  for (int d2 = 0; d2 < 64; ++d2) {
    float4 bv = *(const float4*)&Cs[d2][te * 4];   // 2-way, free
    float bb[4] = {bv.x, bv.y, bv.z, bv.w};
    float aa[4];
    #pragma unroll
    for (int i = 0; i < 4; ++i) aa[i] = Vs[tn * 4 + i][d2];  // broadcast
    #pragma unroll
    for (int i = 0; i < 4; ++i)
      #pragma unroll
      for (int j = 0; j < 4; ++j) acc[i][j] += aa[i] * bb[j];
  }
  const float scale = 1.f / 512.f;
  #pragma unroll
  for (int i = 0; i < 4; ++i)
    #pragma unroll
    for (int j = 0; j < 4; ++j) {
      size_t idx = ((size_t)b * NN + t * 64 + tn * 4 + i) * CC + h * 64 + te * 4 + j;
      float val = acc[i][j] * scale;
      ushort hi = f2b(val);
      Aoh[idx] = hi;
      Aol[idx] = f2b(val - b2f(hi));
    }
}

// ---------------------------------------------------------------------------
extern "C" void kernel_launch(void* const* d_in, const int* in_sizes, int n_in,
                              void* d_out, int out_size, void* d_ws, size_t ws_size,
                              hipStream_t stream) {
  const float* x    = (const float*)d_in[0];
  const float* lpw  = (const float*)d_in[1];
  const float* lvw  = (const float*)d_in[2];
  const float* wqkv = (const float*)d_in[3];
  const float* bqkv = (const float*)d_in[4];
  const float* wproj= (const float*)d_in[5];
  const float* bproj= (const float*)d_in[6];
  const float* omega= (const float*)d_in[7];
  const float* w1   = (const float*)d_in[8];
  const float* b1   = (const float*)d_in[9];
  const float* w2   = (const float*)d_in[10];
  const float* b2   = (const float*)d_in[11];
  const float* wg   = (const float*)d_in[12];
  const float* bg   = (const float*)d_in[13];
  float* out = (float*)d_out;

  constexpr size_t MB = 1024 * 1024;
  char* w = (char*)d_ws;
  int*   peak   = (int*)(w);
  int*   valley = (int*)(w + 16 * 1024);
  float* attn   = (float*)(w + 32 * 1024);
  float* gate   = (float*)(w + 48 * 1024);
  float* pe2    = (float*)(w + 64 * 1024);        // 1 MiB
  float* gpe    = (float*)(w + 1088 * 1024);
  float* ropem  = (float*)(w + 1152 * 1024);      // 1 MiB
  ushort* Xh    = (ushort*)(w + 4 * MB);          // 16 MiB bf16 [B*N, C]
  ushort* qb    = (ushort*)(w + 20 * MB);         // 16 MiB bf16 [B,H,N,D]
  ushort* kb    = (ushort*)(w + 36 * MB);         // 16 MiB
  ushort* vb    = (ushort*)(w + 52 * MB);         // 16 MiB
  ushort* Wh    = (ushort*)(w + 68 * MB);         // 1.5 MiB
  ushort* Ph    = (ushort*)(w + 70 * MB);         // 0.5 MiB
  float* ctxp   = (float*)(w + 71 * MB);          // 8 MiB
  float* ctx    = (float*)(w + 79 * MB);          // 0.5 MiB -> 79.5 MiB total
  // aliases (stream-ordered reuse):
  ushort* Aoh = Xh;   // Xh dead after qkv gemm; k_out runs later
  ushort* Aol = qb;   // qb dead after ctx_part

  hipMemsetAsync(peak, 0, 2 * 4096 * sizeof(int), stream);

  k_counts<<<BB * 64, 512, 0, stream>>>(x, peak, valley);
  k_gsum<<<NN, 256, 0, stream>>>(peak, valley, lpw, lvw, attn);
  k_norm<<<1, 1024, 0, stream>>>(attn, gate);
  k_pe<<<NN, 64, 0, stream>>>(omega, w1, b1, w2, b2, pe2);
  k_gatepe<<<1, 256, 0, stream>>>(pe2, wg, bg, gpe);
  k_ropemul<<<1024, 256, 0, stream>>>(pe2, gpe, ropem);

  k_prep_x<<<8192, 256, 0, stream>>>(x, Xh);
  k_prep_h<<<768, 256, 0, stream>>>(wqkv, Wh, 3 * CC * CC);
  k_prep_h<<<256, 256, 0, stream>>>(wproj, Ph, CC * CC);

  // qkv: M=16384, N=1536 -> 1536 blocks (XCD-swizzled), 1-term A, gate in epilogue
  k_gemm2<1, 1><<<1536, 256, 0, stream>>>(Xh, nullptr, Wh, bqkv, gate, ropem,
                                          nullptr, qb, kb, vb, 12, 0);
  k_ctx_part<<<512, 256, 0, stream>>>(qb, kb, ctxp);
  k_ctx_red<<<32, 256, 0, stream>>>(ctxp, ctx);
  k_out<<<2048, 256, 0, stream>>>(vb, ctx, Aoh, Aol);

  // proj: M=16384, N=512 -> 512 blocks, 2-term A (exact split)
  k_gemm2<2, 0><<<512, 256, 0, stream>>>(Aoh, Aol, Ph, bproj, nullptr, nullptr,
                                         out, nullptr, nullptr, nullptr, 4, CC);
}

// Round 5
// 254.388 us; speedup vs baseline: 3.0590x; 1.0012x over previous
//
#include <hip/hip_runtime.h>
#include <hip/hip_bf16.h>
#include <math.h>

constexpr int BB = 4;
constexpr int NN = 4096;
constexpr int CC = 512;
constexpr int HH = 8;
constexpr int DD = 64;
constexpr int NCNT = NN - 2;

typedef __bf16 bf16x8 __attribute__((ext_vector_type(8)));
typedef float f32x4 __attribute__((ext_vector_type(4)));

__device__ __forceinline__ float b2f(ushort u) {
  unsigned v = ((unsigned)u) << 16;
  return __builtin_bit_cast(float, v);
}
__device__ __forceinline__ ushort f2b(float f) {
  __hip_bfloat16 h = __float2bfloat16(f);
  return __builtin_bit_cast(ushort, h);
}
__device__ __forceinline__ void gload16(const ushort* g, ushort* l) {
  __builtin_amdgcn_global_load_lds(
      (const __attribute__((address_space(1))) unsigned int*)g,
      (__attribute__((address_space(3))) unsigned int*)l, 16, 0, 0);
}

// ---------------------------------------------------------------------------
// K1: second-difference sign counts, fused x -> bf16 conversion
// ---------------------------------------------------------------------------
__global__ void k_counts_prep(const float* __restrict__ x,
                              int* __restrict__ peak, int* __restrict__ valley,
                              ushort* __restrict__ Xh) {
  int b = blockIdx.x >> 6;
  int tile = blockIdx.x & 63;
  int c = threadIdx.x;
  int lane = threadIdx.x & 63;
  for (int ii = 0; ii < 64; ++ii) {
    int i = tile * 64 + ii;
    const float* xp = x + ((size_t)b * NN + i) * CC + c;
    float x0 = xp[0];
    Xh[((size_t)b * NN + i) * CC + c] = f2b(x0);
    if (i < NCNT) {
      float x1 = xp[CC], x2 = xp[2 * CC];
      float d2 = (x2 - x1) - (x1 - x0);
      unsigned long long mneg = __ballot(d2 < 0.0f);
      unsigned long long mpos = __ballot(d2 > 0.0f);
      if (lane == 0) {
        atomicAdd(&peak[i], __popcll(mneg));
        atomicAdd(&valley[i], __popcll(mpos));
      }
    }
  }
}

// ---------------------------------------------------------------------------
// K2a: Gaussian sums
// ---------------------------------------------------------------------------
__global__ void k_gsum(const int* __restrict__ peak, const int* __restrict__ valley,
                       const float* __restrict__ lpw, const float* __restrict__ lvw,
                       float* __restrict__ attn) {
  int p = blockIdx.x;
  int tid = threadIdx.x;
  float ipw = expf(-lpw[0]);
  float ivw = expf(-lvw[0]);
  float acc = 0.f;
  for (int i = tid; i < NCNT; i += 256) {
    float dd = (float)(p - (i + 1));
    float t1 = dd * ipw;
    float t2 = dd * ivw;
    acc += (float)peak[i] * expf(-t1 * t1) + (float)valley[i] * expf(-t2 * t2);
  }
  __shared__ float red[256];
  red[tid] = acc;
  __syncthreads();
  for (int s = 128; s > 0; s >>= 1) {
    if (tid < s) red[tid] += red[tid + s];
    __syncthreads();
  }
  if (tid == 0) attn[p] = red[0];
}

// ---------------------------------------------------------------------------
// K2b: min-max normalize
// ---------------------------------------------------------------------------
__global__ void k_norm(const float* __restrict__ attn, float* __restrict__ gate) {
  int tid = threadIdx.x;  // 1024
  float v0 = attn[tid], v1 = attn[tid + 1024], v2 = attn[tid + 2048], v3 = attn[tid + 3072];
  float mn = fminf(fminf(v0, v1), fminf(v2, v3));
  float mx = fmaxf(fmaxf(v0, v1), fmaxf(v2, v3));
  __shared__ float rmn[1024], rmx[1024];
  rmn[tid] = mn; rmx[tid] = mx;
  __syncthreads();
  for (int s = 512; s > 0; s >>= 1) {
    if (tid < s) {
      rmn[tid] = fminf(rmn[tid], rmn[tid + s]);
      rmx[tid] = fmaxf(rmx[tid], rmx[tid + s]);
    }
    __syncthreads();
  }
  float lo = rmn[0];
  float denom = rmx[0] - rmn[0] + 1e-6f;
  gate[tid]        = (v0 - lo) / denom;
  gate[tid + 1024] = (v1 - lo) / denom;
  gate[tid + 2048] = (v2 - lo) / denom;
  gate[tid + 3072] = (v3 - lo) / denom;
}

// ---------------------------------------------------------------------------
// K3a: spectral PE conv path -> pe2 [64][4096]
// ---------------------------------------------------------------------------
__global__ void k_pe(const float* __restrict__ omega,
                     const float* __restrict__ w1, const float* __restrict__ b1,
                     const float* __restrict__ w2, const float* __restrict__ b2,
                     float* __restrict__ pe2) {
  int n = blockIdx.x;
  int j = threadIdx.x;  // 64
  __shared__ float pec[3][64];
  __shared__ float hs[128];
  for (int t = 0; t < 3; ++t) {
    int m = n + t - 1;
    float v = 0.f;
    if (m >= 0 && m < NN) {
      int l1 = m >> 6, l2 = m & 63;
      float rel = (float)(l1 - l2);
      v = (j < 32) ? sinf(rel * omega[j]) : cosf(rel * omega[j - 32]);
    }
    pec[t][j] = v;
  }
  __syncthreads();
  for (int o = j; o < 128; o += 64) {
    int ci = o >> 1;
    float hv = b1[o];
    #pragma unroll
    for (int t = 0; t < 3; ++t) hv += pec[t][ci] * w1[o * 3 + t];
    hv = 0.5f * hv * (1.f + erff(hv * 0.70710678118654752f));
    hs[o] = hv;
  }
  __syncthreads();
  float acc = b2[j];
  for (int o = 0; o < 128; ++o) acc += hs[o] * w2[j * 128 + o];
  pe2[(size_t)j * NN + n] = acc;
}

// ---------------------------------------------------------------------------
// K3b: channel means -> sigmoid gate gpe[64]
// ---------------------------------------------------------------------------
__global__ void k_gatepe(const float* __restrict__ pe2,
                         const float* __restrict__ wg, const float* __restrict__ bg,
                         float* __restrict__ gpe) {
  int tid = threadIdx.x;  // 256
  int j = tid & 63, part = tid >> 6;
  float s = 0.f;
  const float* row = pe2 + (size_t)j * NN + part * 1024;
  for (int t = 0; t < 1024; ++t) s += row[t];
  __shared__ float ps[4][64];
  __shared__ float mean[64];
  ps[part][j] = s;
  __syncthreads();
  if (tid < 64) mean[j] = (ps[0][j] + ps[1][j] + ps[2][j] + ps[3][j]) * (1.f / 4096.f);
  __syncthreads();
  if (tid < 64) {
    float g = bg[j];
    for (int k2 = 0; k2 < 64; ++k2) g += wg[j * 64 + k2] * mean[k2];
    gpe[j] = 1.f / (1.f + expf(-g));
  }
}

// ---------------------------------------------------------------------------
// K3c: rope multiplier  ropem[n*64+dd] = 1 + pe2[dd,n]*gpe[n>>6]*64^-0.25
// ---------------------------------------------------------------------------
__global__ void k_ropemul(const float* __restrict__ pe2, const float* __restrict__ gpe,
                          float* __restrict__ ropem) {
  int idx = blockIdx.x * 256 + threadIdx.x;
  int n = idx >> 6, dd = idx & 63;
  ropem[idx] = 1.f + pe2[(size_t)dd * NN + n] * gpe[n >> 6] * 0.35355339059327373f;
}

// Prep: f32 -> bf16 (weights)
__global__ void k_prep_h(const float* __restrict__ src,
                         ushort* __restrict__ Sh, int nelem) {
  int idx4 = (blockIdx.x * 256 + threadIdx.x) * 4;
  if (idx4 >= nelem) return;
  float4 v = *(const float4*)&src[idx4];
  ushort4 h;
  ((ushort*)&h)[0] = f2b(v.x);
  ((ushort*)&h)[1] = f2b(v.y);
  ((ushort*)&h)[2] = f2b(v.z);
  ((ushort*)&h)[3] = f2b(v.w);
  *(ushort4*)&Sh[idx4] = h;
}

// ---------------------------------------------------------------------------
// Deep-pipelined bf16 MFMA GEMM. C = A[M][512] * (Bh(+Bl))[ncols][512]^T.
// 128x128 tile, BK=32, NT=16 steps, 3 LDS buffers, depth-2 prefetch with
// counted vmcnt (never 0 in-loop). 4 waves (2x2), XOR bank swizzle, XCD grid
// swizzle. BPERB: B has per-batch leading offset (b = m0>>12).
// EPI=0: f32 out (+bias). EPI=1: qkv epilogue.
// ---------------------------------------------------------------------------
template <int BTERMS, int EPI, int BPERB>
__global__ __launch_bounds__(256) void k_gemm2(
    const ushort* __restrict__ Ag, const ushort* __restrict__ Bgh,
    const ushort* __restrict__ Bgl,
    const float* __restrict__ bias, const float* __restrict__ gate,
    const float* __restrict__ ropem,
    float* __restrict__ outF, ushort* __restrict__ qb, ushort* __restrict__ kb,
    ushort* __restrict__ vb, int ntn, int ncols) {
  const int nwg = gridDim.x;
  const int hw = blockIdx.x;
  const int logical = (hw & 7) * (nwg >> 3) + (hw >> 3);
  const int m0 = (logical / ntn) * 128, n0 = (logical % ntn) * 128;

  const int tid = threadIdx.x, wave = tid >> 6, lane = tid & 63;
  const int wm = wave >> 1, wn = wave & 1;
  __shared__ ushort sA[3][4096];
  __shared__ ushort sB[3][BTERMS * 4096];
  f32x4 acc[4][4] = {};

  const int lr = lane >> 2;
  const int ci = lane & 3;
  const int scol = (ci ^ ((lr >> 1) & 3)) * 8;   // inverse-swizzled source col
  const int rA = lane & 15;
  const int cswz = ((lane >> 4) ^ ((rA >> 1) & 3)) * 8;  // read-side swizzle

  const int chunk0 = wave * 2, chunk1 = wave * 2 + 1;
  const int row0 = chunk0 * 16 + lr, row1 = chunk1 * 16 + lr;

  const ushort* Bh_ = Bgh + (BPERB ? (size_t)(m0 >> 12) * 262144 : 0);
  const ushort* Bl_ = (BTERMS == 2) ? (Bgl + (BPERB ? (size_t)(m0 >> 12) * 262144 : 0))
                                    : nullptr;

#define STAGE(T, S)                                                        \
  {                                                                        \
    int k0s = (T) * 32;                                                    \
    size_t ga0 = (size_t)(m0 + row0) * CC + k0s + scol;                    \
    size_t ga1 = (size_t)(m0 + row1) * CC + k0s + scol;                    \
    size_t gb0 = (size_t)(n0 + row0) * CC + k0s + scol;                    \
    size_t gb1 = (size_t)(n0 + row1) * CC + k0s + scol;                    \
    gload16(Ag + ga0, &sA[S][chunk0 * 512]);                               \
    gload16(Ag + ga1, &sA[S][chunk1 * 512]);                               \
    gload16(Bh_ + gb0, &sB[S][chunk0 * 512]);                              \
    gload16(Bh_ + gb1, &sB[S][chunk1 * 512]);                              \
    if (BTERMS == 2) {                                                     \
      gload16(Bl_ + gb0, &sB[S][4096 + chunk0 * 512]);                     \
      gload16(Bl_ + gb1, &sB[S][4096 + chunk1 * 512]);                     \
    }                                                                      \
  }

#define VMWAIT_DEPTH()                                                     \
  {                                                                        \
    if constexpr (BTERMS == 1)                                             \
      asm volatile("s_waitcnt vmcnt(4)" ::: "memory");                     \
    else                                                                   \
      asm volatile("s_waitcnt vmcnt(6)" ::: "memory");                     \
    __builtin_amdgcn_sched_barrier(0);                                     \
  }

  STAGE(0, 0);
  STAGE(1, 1);
  VMWAIT_DEPTH();                 // tile 0 landed; tile 1 still in flight
  __builtin_amdgcn_s_barrier();

  #pragma unroll
  for (int t = 0; t < 16; ++t) {
    if (t < 14) STAGE(t + 2, (t + 2) % 3);
    const int cur = t % 3;
    bf16x8 a0[4], bh[4], bl[4];
    #pragma unroll
    for (int m = 0; m < 4; ++m) {
      int off = (wm * 64 + m * 16 + rA) * 32 + cswz;
      a0[m] = *(const bf16x8*)(&sA[cur][off]);
    }
    #pragma unroll
    for (int n = 0; n < 4; ++n) {
      int off = (wn * 64 + n * 16 + rA) * 32 + cswz;
      bh[n] = *(const bf16x8*)(&sB[cur][off]);
      if (BTERMS == 2) bl[n] = *(const bf16x8*)(&sB[cur][4096 + off]);
    }
    __builtin_amdgcn_s_setprio(1);
    #pragma unroll
    for (int m = 0; m < 4; ++m)
      #pragma unroll
      for (int n = 0; n < 4; ++n) {
        acc[m][n] = __builtin_amdgcn_mfma_f32_16x16x32_bf16(a0[m], bh[n], acc[m][n], 0, 0, 0);
        if (BTERMS == 2)
          acc[m][n] = __builtin_amdgcn_mfma_f32_16x16x32_bf16(a0[m], bl[n], acc[m][n], 0, 0, 0);
      }
    __builtin_amdgcn_s_setprio(0);
    if (t < 15) {
      if (t < 14) {
        VMWAIT_DEPTH();           // next tile landed; t+2 still in flight
      } else {
        asm volatile("s_waitcnt vmcnt(0)" ::: "memory");
        __builtin_amdgcn_sched_barrier(0);
      }
      __builtin_amdgcn_s_barrier();
    }
  }
#undef STAGE
#undef VMWAIT_DEPTH

  #pragma unroll
  for (int m = 0; m < 4; ++m) {
    #pragma unroll
    for (int n = 0; n < 4; ++n) {
      #pragma unroll
      for (int r = 0; r < 4; ++r) {
        int row = m0 + wm * 64 + m * 16 + (lane >> 4) * 4 + r;
        int col = n0 + wn * 64 + n * 16 + (lane & 15);
        if (EPI == 0) {
          float val = acc[m][n][r] + bias[col];
          outF[(size_t)row * ncols + col] = val;
        } else {
          int nseq = row & (NN - 1), b = row >> 12;
          float val = acc[m][n][r] * gate[nseq] + bias[col];
          int part = col >> 9, c = col & 511, h = c >> 6, dd = c & 63;
          if (part == 2) {
            vb[(size_t)row * CC + c] = f2b(val);   // plain [row][c] = proj's A
          } else {
            size_t oi = (((size_t)b * HH + h) * NN + nseq) * DD + dd;
            float e = val > 0.f ? val + 1.f : expf(val);  // elu+1
            float res = e * ropem[nseq * 64 + dd];
            (part == 0 ? qb : kb)[oi] = f2b(res);
          }
        }
      }
    }
  }
}

// ---------------------------------------------------------------------------
// K5a: ctx partials. Thread owns contiguous 4x4 (d,e) patch.
// ---------------------------------------------------------------------------
__global__ __launch_bounds__(256) void k_ctx_part(
    const ushort* __restrict__ qb, const ushort* __restrict__ kb,
    float* __restrict__ ctxp) {
  int bh = blockIdx.x >> 4;
  int chunk = blockIdx.x & 15;
  const int tid = threadIdx.x;
  const int td = tid >> 4;
  const int te = tid & 15;
  __shared__ float Qs[16][68], Ks[16][68];
  float acc[4][4] = {};
  const size_t base = (size_t)bh * NN * DD;
  for (int n0 = chunk * 256; n0 < chunk * 256 + 256; n0 += 16) {
    int idx4 = tid * 4;
    int nl = idx4 >> 6, dd = idx4 & 63;
    ushort4 qv = *(const ushort4*)&qb[base + (size_t)(n0 + nl) * DD + dd];
    ushort4 kv = *(const ushort4*)&kb[base + (size_t)(n0 + nl) * DD + dd];
    Qs[nl][dd] = b2f(qv.x); Qs[nl][dd + 1] = b2f(qv.y);
    Qs[nl][dd + 2] = b2f(qv.z); Qs[nl][dd + 3] = b2f(qv.w);
    Ks[nl][dd] = b2f(kv.x); Ks[nl][dd + 1] = b2f(kv.y);
    Ks[nl][dd + 2] = b2f(kv.z); Ks[nl][dd + 3] = b2f(kv.w);
    __syncthreads();
    #pragma unroll
    for (int nn2 = 0; nn2 < 16; ++nn2) {
      float4 a = *(const float4*)&Qs[nn2][td * 4];
      float4 bv = *(const float4*)&Ks[nn2][te * 4];
      float aa[4] = {a.x, a.y, a.z, a.w};
      float bb[4] = {bv.x, bv.y, bv.z, bv.w};
      #pragma unroll
      for (int i = 0; i < 4; ++i)
        #pragma unroll
        for (int j = 0; j < 4; ++j) acc[i][j] += aa[i] * bb[j];
    }
    __syncthreads();
  }
  const float scale = 1.f / 512.f;
  #pragma unroll
  for (int i = 0; i < 4; ++i)
    #pragma unroll
    for (int j = 0; j < 4; ++j)
      ctxp[(size_t)(bh * 16 + chunk) * 4096 + (td * 4 + i) * 64 + (te * 4 + j)] =
          acc[i][j] * scale;
}

// K5b: deterministic reduce -> ctx[bh][64][64] f32
__global__ void k_ctx_red(const float* __restrict__ ctxp, float* __restrict__ ctx) {
  int bh = blockIdx.x;
  int tid = threadIdx.x;
  for (int r = 0; r < 16; ++r) {
    int idx = tid + 256 * r;
    float s = 0.f;
    for (int c2 = 0; c2 < 16; ++c2) s += ctxp[(size_t)(bh * 16 + c2) * 4096 + idx];
    ctx[(size_t)bh * 4096 + idx] = s;
  }
}

// ---------------------------------------------------------------------------
// K6: M_b[(h,d)][o] = (1/512) * sum_e ctx[b,h,d,e] * wp[o, h*64+e]
// stored as Bt[b][o][h*64+d], bf16 hi/lo. grid 128 = (b,h,oq); 256 thr.
// ---------------------------------------------------------------------------
__global__ __launch_bounds__(256) void k_mproj(
    const float* __restrict__ ctx, const float* __restrict__ wp,
    ushort* __restrict__ Mh, ushort* __restrict__ Ml) {
  int blk = blockIdx.x;
  int b = blk >> 5, h = (blk >> 2) & 7, oq = blk & 3;
  int tid = threadIdx.x;
  int o = oq * 128 + (tid & 127);
  int d0 = (tid >> 7) * 32;
  __shared__ float cs[64][64];
  #pragma unroll
  for (int it = 0; it < 4; ++it) {
    int idx = (tid + 256 * it) * 4;
    *(float4*)&cs[idx >> 6][idx & 63] =
        *(const float4*)&ctx[(size_t)(b * 8 + h) * 4096 + idx];
  }
  __syncthreads();
  float wv[64];
  #pragma unroll
  for (int e = 0; e < 64; ++e) wv[e] = wp[(size_t)o * 512 + h * 64 + e];
  for (int d = d0; d < d0 + 32; ++d) {
    float s = 0.f;
    #pragma unroll
    for (int e = 0; e < 64; ++e) s += cs[d][e] * wv[e];
    s *= (1.f / 512.f);
    ushort hi = f2b(s);
    size_t idx = ((size_t)b * 512 + o) * 512 + h * 64 + d;
    Mh[idx] = hi;
    Ml[idx] = f2b(s - b2f(hi));
  }
}

// ---------------------------------------------------------------------------
extern "C" void kernel_launch(void* const* d_in, const int* in_sizes, int n_in,
                              void* d_out, int out_size, void* d_ws, size_t ws_size,
                              hipStream_t stream) {
  const float* x    = (const float*)d_in[0];
  const float* lpw  = (const float*)d_in[1];
  const float* lvw  = (const float*)d_in[2];
  const float* wqkv = (const float*)d_in[3];
  const float* bqkv = (const float*)d_in[4];
  const float* wproj= (const float*)d_in[5];
  const float* bproj= (const float*)d_in[6];
  const float* omega= (const float*)d_in[7];
  const float* w1   = (const float*)d_in[8];
  const float* b1   = (const float*)d_in[9];
  const float* w2   = (const float*)d_in[10];
  const float* b2   = (const float*)d_in[11];
  const float* wg   = (const float*)d_in[12];
  const float* bg   = (const float*)d_in[13];
  float* out = (float*)d_out;

  constexpr size_t MB = 1024 * 1024;
  char* w = (char*)d_ws;
  int*   peak   = (int*)(w);
  int*   valley = (int*)(w + 16 * 1024);
  float* attn   = (float*)(w + 32 * 1024);
  float* gate   = (float*)(w + 48 * 1024);
  float* pe2    = (float*)(w + 64 * 1024);        // 1 MiB
  float* gpe    = (float*)(w + 1088 * 1024);
  float* ropem  = (float*)(w + 1152 * 1024);      // 1 MiB
  ushort* Xh    = (ushort*)(w + 4 * MB);          // 16 MiB bf16 [B*N, C]
  ushort* qb    = (ushort*)(w + 20 * MB);         // 16 MiB bf16 [B,H,N,D]
  ushort* kb    = (ushort*)(w + 36 * MB);         // 16 MiB
  ushort* vb    = (ushort*)(w + 52 * MB);         // 16 MiB bf16 [B*N, C]
  ushort* Wh    = (ushort*)(w + 68 * MB);         // 1.5 MiB
  ushort* Mh    = (ushort*)(w + 70 * MB);         // 0.5 MiB [B][512][512]... 2 MiB total
  ushort* Ml    = (ushort*)(w + 72 * MB);         // 2 MiB
  float* ctxp   = (float*)(w + 75 * MB);          // 8 MiB
  float* ctx    = (float*)(w + 83 * MB);          // 0.5 MiB -> 83.5 MiB total

  hipMemsetAsync(peak, 0, 2 * 4096 * sizeof(int), stream);

  k_counts_prep<<<BB * 64, 512, 0, stream>>>(x, peak, valley, Xh);
  k_gsum<<<NN, 256, 0, stream>>>(peak, valley, lpw, lvw, attn);
  k_norm<<<1, 1024, 0, stream>>>(attn, gate);
  k_pe<<<NN, 64, 0, stream>>>(omega, w1, b1, w2, b2, pe2);
  k_gatepe<<<1, 256, 0, stream>>>(pe2, wg, bg, gpe);
  k_ropemul<<<1024, 256, 0, stream>>>(pe2, gpe, ropem);
  k_prep_h<<<768, 256, 0, stream>>>(wqkv, Wh, 3 * CC * CC);

  // qkv: M=16384, N=1536 (XCD-swizzled); gate in epilogue
  k_gemm2<1, 1, 0><<<1536, 256, 0, stream>>>(Xh, Wh, nullptr, bqkv, gate, ropem,
                                             nullptr, qb, kb, vb, 12, 0);
  k_ctx_part<<<512, 256, 0, stream>>>(qb, kb, ctxp);
  k_ctx_red<<<32, 256, 0, stream>>>(ctxp, ctx);
  k_mproj<<<128, 256, 0, stream>>>(ctx, wproj, Mh, Ml);

  // fused out+proj: out = V[16384x512] * M_b^T (per-batch B) + bias
  k_gemm2<2, 0, 1><<<512, 256, 0, stream>>>(vb, Mh, Ml, bproj, nullptr, nullptr,
                                            out, nullptr, nullptr, nullptr, 4, CC);
}